// Round 1
// baseline (766.785 us; speedup 1.0000x reference)
//
#include <hip/hip_runtime.h>
#include <cstdint>

typedef __bf16 bf16;
typedef bf16 bf16x8 __attribute__((ext_vector_type(8)));
typedef float f32x4 __attribute__((ext_vector_type(4)));

#define S_LEN   16384
#define HID     1280
#define NHEAD   16
#define HD      80
#define HDP     96
#define CHUNK   1024
#define NCHUNKS 16

// workspace element offsets (bf16 elements)
#define OFF_XB     0LL           // x bf16            [16384][1280]
#define OFF_WQKV   20971520LL    // w_qkv bf16        [3840][1280]
#define OFF_WPROJ  25886720LL    // w_proj bf16       [1280][1280]
#define OFF_QPAD   27525120LL    // q bf16 padded     [16384][16][96]
#define OFF_KPAD   52690944LL    // k bf16 padded     [16384][16][96]
#define OFF_VT     77856768LL    // v^T bf16          [16][16][80][1024]
#define OFF_ATTN   98828288LL    // attn out bf16     [16384][1280]

// global -> LDS direct copy, 16 B per lane; lane i lands at base + i*16.
__device__ __forceinline__ void gl_lds16(const void* g, void* l) {
  __builtin_amdgcn_global_load_lds(
      (const __attribute__((address_space(1))) unsigned int*)g,
      (__attribute__((address_space(3))) unsigned int*)l, 16, 0, 0);
}

// ---------------------------------------------------------------------------
// Kernel 1: fp32 -> bf16 conversion + zero-fill of q/k pad dims (80..95)
// ---------------------------------------------------------------------------
__global__ void convert_kernel(const float* __restrict__ x,
                               const float* __restrict__ wqkv,
                               const float* __restrict__ wproj,
                               bf16* __restrict__ ws) {
  const long long N1 = 20971520LL;
  const long long N2 = 4915200LL;
  const long long N3 = 1638400LL;
  const long long N4 = 4194304LL;
  long long i = ((long long)blockIdx.x * 256 + threadIdx.x) << 2;
  if (i < N1) {
    float4 v = *(const float4*)(x + i);
    bf16* o = ws + OFF_XB + i;
    o[0] = (bf16)v.x; o[1] = (bf16)v.y; o[2] = (bf16)v.z; o[3] = (bf16)v.w;
    return;
  }
  i -= N1;
  if (i < N2) {
    float4 v = *(const float4*)(wqkv + i);
    bf16* o = ws + OFF_WQKV + i;
    o[0] = (bf16)v.x; o[1] = (bf16)v.y; o[2] = (bf16)v.z; o[3] = (bf16)v.w;
    return;
  }
  i -= N2;
  if (i < N3) {
    float4 v = *(const float4*)(wproj + i);
    bf16* o = ws + OFF_WPROJ + i;
    o[0] = (bf16)v.x; o[1] = (bf16)v.y; o[2] = (bf16)v.z; o[3] = (bf16)v.w;
    return;
  }
  i -= N3;
  if (i < N4) {
    long long g = i >> 4; int j = (int)(i & 15);
    *(uint2*)(ws + OFF_QPAD + g * HDP + HD + j) = make_uint2(0u, 0u);
    return;
  }
  i -= N4;
  if (i < N4) {
    long long g = i >> 4; int j = (int)(i & 15);
    *(uint2*)(ws + OFF_KPAD + g * HDP + HD + j) = make_uint2(0u, 0u);
    return;
  }
}

// ---------------------------------------------------------------------------
// Kernels 2 & 5: bf16 GEMM C = A @ B^T (+bias), 256x256 tile, BK=64,
// 8-granule phase-pipelined schedule (T3+T4+T2+T5):
//   - 512 thr = 8 waves (2M x 4N), wave tile 128x64, acc[8][4].
//   - LDS: 8 granules x 16 KB = 128 KB.  granule(parity, op, khalf) holds
//     [256 rows][32 k] bf16, rows of 64 B, column bytes XOR-swizzled by
//     ((row&3)<<4) -> every fragment b128 read is bank-balanced (8 lanes on
//     each of the 8 16-B slots).  global_load_lds writes linearly, so the
//     per-thread GLOBAL source address carries the inverse swizzle.
//   - 4 phases per K-tile: {ds_read subtile; stage 1 granule (2 x gl_lds);
//     s_barrier; setprio(1); 16 MFMA; setprio(0); [vmcnt(4)]; s_barrier}.
//     Counted vmcnt(4) only at phases 2 and 4 (never 0 in steady state):
//     each granule is staged 3-4 phases before first read and overwritten
//     right after its last reader phase.  Issue/drain ledger:
//       prologue: A0,B0,A1,B1(t0) issued (8), vmcnt(4) -> A0,B0 landed.
//       tile T: P1 +A0(T+1); P2 +B0(T+1), vmcnt(4) -> A1,B1(T) landed;
//               P3 +A1(T+1); P4 +B1(T+1), vmcnt(4) -> A0,B0(T+1) landed.
//     Tail tile (no stage) uses vmcnt(0) at P2.
// Grid x = M-strip (fast) so blocks sharing an A-strip land on one XCD.
// ---------------------------------------------------------------------------
template <int MODE>
__global__ __launch_bounds__(512, 2) void gemm_bt_kernel(
    const bf16* __restrict__ A, const bf16* __restrict__ B,
    const float* __restrict__ bias, bf16* __restrict__ ws,
    float* __restrict__ outF) {
  // granule index: parity*4 + op*2 + khalf   (op: 0=A, 1=B)
  __shared__ __align__(16) bf16 G[8][8192];

  const int tid = threadIdx.x;
  const int lane = tid & 63;
  const int w = tid >> 6;                 // 0..7
  const int wm = w >> 2, wn = w & 3;      // wave row (0,1) / col (0..3)
  const int quad = lane >> 4, l16 = lane & 15;
  const long long m0 = (long long)blockIdx.x * 256;
  const long long n0 = (long long)blockIdx.y * 256;
  const int wb = w * 1024;                // wave-uniform LDS byte base / issue

  // staging: chunk ci = j*512 + tid (j=0,1), R = ci>>2 (row), sl = ci&3 (slot)
  // LDS byte ci*16 stores global k-group (sl ^ (R&3)) of row R  (inv-swizzle)
  const int r0 = tid >> 2;
  const int sl = tid & 3;
  const long long off0 = (long long)r0 * 1280 + (long long)((sl ^ (r0 & 3)) << 3);
  const bf16* srcA = A + m0 * 1280 + off0;   // j=1 source = +128 rows = +163840
  const bf16* srcB = B + n0 * 1280 + off0;

  // fragment read bases (byte): row*64 + swizzled column
  const int rbA = (wm * 128 + l16) * 64;
  const int rbB = (wn * 64 + l16) * 64;
  const int csw = (quad * 16) ^ ((l16 & 3) << 4);

  f32x4 acc[8][4] = {};

  // ---- prologue: stage tile 0 granules in order A0,B0,A1,B1 ----
  {
    char* dA0 = (char*)G[0] + wb; char* dA1 = (char*)G[1] + wb;
    char* dB0 = (char*)G[2] + wb; char* dB1 = (char*)G[3] + wb;
    gl_lds16(srcA, dA0);           gl_lds16(srcA + 163840, dA0 + 8192);
    gl_lds16(srcB, dB0);           gl_lds16(srcB + 163840, dB0 + 8192);
    gl_lds16(srcA + 32, dA1);      gl_lds16(srcA + 32 + 163840, dA1 + 8192);
    gl_lds16(srcB + 32, dB1);      gl_lds16(srcB + 32 + 163840, dB1 + 8192);
  }
  asm volatile("s_waitcnt vmcnt(4)" ::: "memory");
  __builtin_amdgcn_s_barrier();

  for (int T = 0; T < 20; ++T) {
    const int p = (T & 1) * 4;
    const bf16* gA0 = G[p + 0];
    const bf16* gA1 = G[p + 1];
    const bf16* gB0 = G[p + 2];
    const bf16* gB1 = G[p + 3];
    char* dA0 = (char*)G[(p ^ 4) + 0] + wb;
    char* dA1 = (char*)G[(p ^ 4) + 1] + wb;
    char* dB0 = (char*)G[(p ^ 4) + 2] + wb;
    char* dB1 = (char*)G[(p ^ 4) + 3] + wb;
    const bf16* sA = srcA + (long long)(T + 1) * 64;
    const bf16* sB = srcB + (long long)(T + 1) * 64;
    const bool st = T < 19;

    bf16x8 af[4], bfr[4];

    // ---- P1: khalf 0, it 0-3 (+ all bfr khalf0); stage A-k0(T+1) ----
#pragma unroll
    for (int i = 0; i < 4; ++i)
      af[i] = *(const bf16x8*)((const char*)gA0 + rbA + i * 1024 + csw);
#pragma unroll
    for (int j = 0; j < 4; ++j)
      bfr[j] = *(const bf16x8*)((const char*)gB0 + rbB + j * 1024 + csw);
    if (st) { gl_lds16(sA, dA0); gl_lds16(sA + 163840, dA0 + 8192); }
    __builtin_amdgcn_s_barrier();
    __builtin_amdgcn_s_setprio(1);
#pragma unroll
    for (int i = 0; i < 4; ++i)
#pragma unroll
      for (int j = 0; j < 4; ++j)
        acc[i][j] = __builtin_amdgcn_mfma_f32_16x16x32_bf16(
            af[i], bfr[j], acc[i][j], 0, 0, 0);
    __builtin_amdgcn_s_setprio(0);
    __builtin_amdgcn_s_barrier();

    // ---- P2: khalf 0, it 4-7 (bfr reused); stage B-k0(T+1) ----
#pragma unroll
    for (int i = 0; i < 4; ++i)
      af[i] = *(const bf16x8*)((const char*)gA0 + rbA + (4 + i) * 1024 + csw);
    if (st) { gl_lds16(sB, dB0); gl_lds16(sB + 163840, dB0 + 8192); }
    __builtin_amdgcn_s_barrier();
    __builtin_amdgcn_s_setprio(1);
#pragma unroll
    for (int i = 0; i < 4; ++i)
#pragma unroll
      for (int j = 0; j < 4; ++j)
        acc[4 + i][j] = __builtin_amdgcn_mfma_f32_16x16x32_bf16(
            af[i], bfr[j], acc[4 + i][j], 0, 0, 0);
    __builtin_amdgcn_s_setprio(0);
    if (st) { asm volatile("s_waitcnt vmcnt(4)" ::: "memory"); }
    else    { asm volatile("s_waitcnt vmcnt(0)" ::: "memory"); }
    __builtin_amdgcn_s_barrier();

    // ---- P3: khalf 1, it 0-3 (+ all bfr khalf1); stage A-k1(T+1) ----
#pragma unroll
    for (int i = 0; i < 4; ++i)
      af[i] = *(const bf16x8*)((const char*)gA1 + rbA + i * 1024 + csw);
#pragma unroll
    for (int j = 0; j < 4; ++j)
      bfr[j] = *(const bf16x8*)((const char*)gB1 + rbB + j * 1024 + csw);
    if (st) { gl_lds16(sA + 32, dA1); gl_lds16(sA + 32 + 163840, dA1 + 8192); }
    __builtin_amdgcn_s_barrier();
    __builtin_amdgcn_s_setprio(1);
#pragma unroll
    for (int i = 0; i < 4; ++i)
#pragma unroll
      for (int j = 0; j < 4; ++j)
        acc[i][j] = __builtin_amdgcn_mfma_f32_16x16x32_bf16(
            af[i], bfr[j], acc[i][j], 0, 0, 0);
    __builtin_amdgcn_s_setprio(0);
    __builtin_amdgcn_s_barrier();

    // ---- P4: khalf 1, it 4-7 (bfr reused); stage B-k1(T+1) ----
#pragma unroll
    for (int i = 0; i < 4; ++i)
      af[i] = *(const bf16x8*)((const char*)gA1 + rbA + (4 + i) * 1024 + csw);
    if (st) { gl_lds16(sB + 32, dB1); gl_lds16(sB + 32 + 163840, dB1 + 8192); }
    __builtin_amdgcn_s_barrier();
    __builtin_amdgcn_s_setprio(1);
#pragma unroll
    for (int i = 0; i < 4; ++i)
#pragma unroll
      for (int j = 0; j < 4; ++j)
        acc[4 + i][j] = __builtin_amdgcn_mfma_f32_16x16x32_bf16(
            af[i], bfr[j], acc[4 + i][j], 0, 0, 0);
    __builtin_amdgcn_s_setprio(0);
    asm volatile("s_waitcnt vmcnt(4)" ::: "memory");
    __builtin_amdgcn_s_barrier();
  }

  // ---- epilogue ----
  if (MODE == 0) {
    bf16* qpad = ws + OFF_QPAD;
    bf16* kpad = ws + OFF_KPAD;
    bf16* vt = ws + OFF_VT;
#pragma unroll
    for (int jt = 0; jt < 4; ++jt) {
      int n = (int)n0 + wn * 64 + jt * 16 + l16;
      float bv = bias[n];
      int part = n / HID;
      int idx = n - part * HID;
      int h = idx / HD;
      int d = idx - h * HD;
#pragma unroll
      for (int it = 0; it < 8; ++it) {
#pragma unroll
        for (int r = 0; r < 4; ++r) {
          long long m = m0 + wm * 128 + it * 16 + quad * 4 + r;
          float v = acc[it][jt][r] + bv;
          if (part == 0) {
            qpad[(m * NHEAD + h) * HDP + d] = (bf16)v;
          } else if (part == 1) {
            kpad[(m * NHEAD + h) * HDP + d] = (bf16)v;
          } else {
            long long c = m >> 10, t2 = m & 1023;
            vt[((c * NHEAD + h) * HD + d) * CHUNK + t2] = (bf16)v;
          }
        }
      }
    }
  } else {
#pragma unroll
    for (int jt = 0; jt < 4; ++jt) {
      int n = (int)n0 + wn * 64 + jt * 16 + l16;
      float bv = bias[n];
#pragma unroll
      for (int it = 0; it < 8; ++it) {
#pragma unroll
        for (int r = 0; r < 4; ++r) {
          long long m = m0 + wm * 128 + it * 16 + quad * 4 + r;
          outF[m * HID + n] = acc[it][jt][r] + bv;
        }
      }
    }
  }
}

// ---------------------------------------------------------------------------
// Kernel 3: RoPE in-place, vectorized bf16x8.
// ---------------------------------------------------------------------------
__global__ void rope_kernel(const float* __restrict__ cosp,
                            const float* __restrict__ sinp,
                            bf16* __restrict__ ws) {
  long long i = (long long)blockIdx.x * 256 + threadIdx.x;
  int g = (int)(i % 5);
  long long r = i / 5;
  int h = (int)(r % NHEAD);
  long long r2 = r / NHEAD;
  int tok = (int)(r2 % S_LEN);
  int isK = (int)(r2 / S_LEN);
  bf16* base = ws + (isK ? OFF_KPAD : OFF_QPAD) + ((long long)tok * NHEAD + h) * HDP;
  bf16x8 a8 = *(const bf16x8*)(base + g * 8);
  bf16x8 b8 = *(const bf16x8*)(base + 40 + g * 8);
  const float* cb = cosp + (long long)tok * HD;
  const float* sb = sinp + (long long)tok * HD;
  bf16x8 oA, oB;
#pragma unroll
  for (int j = 0; j < 8; ++j) {
    float a = (float)a8[j], b = (float)b8[j];
    int d = g * 8 + j;
    oA[j] = (bf16)(a * cb[d] - b * sb[d]);
    oB[j] = (bf16)(b * cb[d + 40] + a * sb[d + 40]);
  }
  *(bf16x8*)(base + g * 8) = oA;
  *(bf16x8*)(base + 40 + g * 8) = oB;
}

// ---------------------------------------------------------------------------
// Kernel 4: flash attention. Q-tile 256 (64 rows/wave, it=4), K-tile 64,
// 4 q-blocks per (chunk,head) -> K/V re-read 4x. Grid x = (c,h) so the 4
// sharers have ids congruent mod 8 -> same XCD L2. Fixed-max softmax;
// double-buffered K/V DMA staging; one barrier per tile.
// LDS 26.6+28.7+45 KB = 100 KB -> 1 block/CU.
// ---------------------------------------------------------------------------
__global__ __launch_bounds__(256, 1) void attn_kernel(bf16* __restrict__ ws) {
  __shared__ __align__(16) bf16 Ks[2][64 * 104];       // 13312 B each
  __shared__ __align__(16) bf16 Vs[2][80 * 88 + 128];  // 14336 B each
  __shared__ __align__(16) bf16 Ps[256 * 88];          // 45056 B
  const int ch = blockIdx.x;
  const int c = ch >> 4, h = ch & 15;
  const int qt = blockIdx.y;
  const int tid = threadIdx.x, lane = tid & 63, w = tid >> 6;
  const int quad = lane >> 4, l16 = lane & 15;

  const bf16* qpad = ws + OFF_QPAD;
  const bf16* kpad = ws + OFF_KPAD;
  const bf16* vt = ws + OFF_VT;
  bf16* attn = ws + OFF_ATTN;

  // --- staging source precompute ---
  const char* kbase =
      (const char*)(kpad + (((long long)c * CHUNK) * NHEAD + h) * HDP);
  const char* ksrc[4];
#pragma unroll
  for (int j = 0; j < 4; ++j) {
    int ci = tid + j * 256;
    int ciq = ci < 832 ? ci : 831;
    int row = ciq / 13;
    int cb = (ciq - row * 13) * 16;
    if (cb >= 192) cb = 0;
    ksrc[j] = kbase + row * 3072 + cb;
  }
  const char* vbase = (const char*)(vt + ((long long)c * NHEAD + h) * HD * CHUNK);
  const char* vsrc[4];
#pragma unroll
  for (int j = 0; j < 4; ++j) {
    int ci = tid + j * 256;
    int row = ci / 11;
    if (row > 79) row = 79;
    int cb = (ci - row * 11) * 16;
    if (cb >= 128) cb = 0;
    vsrc[j] = vbase + row * 2048 + cb;
  }
  const int wb = w * 1024;

  // prologue: stage tile 0 into buffer 0
  {
#pragma unroll
    for (int j = 0; j < 3; ++j)
      gl_lds16(ksrc[j], (char*)Ks[0] + j * 4096 + wb);
    if (tid < 64) gl_lds16(ksrc[3], (char*)Ks[0] + 3 * 4096 + wb);
#pragma unroll
    for (int j = 0; j < 3; ++j)
      gl_lds16(vsrc[j], (char*)Vs[0] + j * 4096 + wb);
    if (tid < 128) gl_lds16(vsrc[3], (char*)Vs[0] + 3 * 4096 + wb);
  }

  // --- Q fragments, pre-scaled (overlaps the prologue DMA) ---
  const float scale = 0.111803398875f;  // 1/sqrt(80)
  bf16x8 qf[4][3];
#pragma unroll
  for (int it = 0; it < 4; ++it) {
    long long tok = (long long)c * CHUNK + qt * 256 + w * 64 + it * 16 + l16;
    const bf16* qrow = qpad + (tok * NHEAD + h) * HDP;
#pragma unroll
    for (int ks = 0; ks < 3; ++ks) {
      bf16x8 t = *(const bf16x8*)(qrow + ks * 32 + quad * 8);
#pragma unroll
      for (int j = 0; j < 8; ++j) t[j] = (bf16)((float)t[j] * scale);
      qf[it][ks] = t;
    }
  }

  f32x4 o[4][5] = {};
  float lrow[4][4] = {};

  for (int t = 0; t < 16; ++t) {
    const int cur = t & 1;
    __syncthreads();
    if (t + 1 < 16) {
      const int kadv = (t + 1) * 64 * 3072;
      const int vadv = (t + 1) * 64 * 2;
#pragma unroll
      for (int j = 0; j < 3; ++j)
        gl_lds16(ksrc[j] + kadv, (char*)Ks[cur ^ 1] + j * 4096 + wb);
      if (tid < 64) gl_lds16(ksrc[3] + kadv, (char*)Ks[cur ^ 1] + 3 * 4096 + wb);
#pragma unroll
      for (int j = 0; j < 3; ++j)
        gl_lds16(vsrc[j] + vadv, (char*)Vs[cur ^ 1] + j * 4096 + wb);
      if (tid < 128) gl_lds16(vsrc[3] + vadv, (char*)Vs[cur ^ 1] + 3 * 4096 + wb);
    }
    const bf16* K_ = Ks[cur];
    const bf16* V_ = Vs[cur];

#pragma unroll
    for (int jt = 0; jt < 4; ++jt) {
      bf16x8 kb[3];
#pragma unroll
      for (int ks = 0; ks < 3; ++ks)
        kb[ks] = *(const bf16x8*)(K_ + (jt * 16 + l16) * 104 + ks * 32 + quad * 8);
#pragma unroll
      for (int it = 0; it < 4; ++it) {
        f32x4 z = {};
#pragma unroll
        for (int ks = 0; ks < 3; ++ks)
          z = __builtin_amdgcn_mfma_f32_16x16x32_bf16(qf[it][ks], kb[ks], z, 0, 0, 0);
#pragma unroll
        for (int r = 0; r < 4; ++r) {
          float p2 = __expf(z[r]);
          lrow[it][r] += p2;
          Ps[(w * 64 + it * 16 + quad * 4 + r) * 88 + jt * 16 + l16] = (bf16)p2;
        }
      }
    }

#pragma unroll
    for (int k2 = 0; k2 < 2; ++k2) {
      bf16x8 pa[4];
#pragma unroll
      for (int it = 0; it < 4; ++it)
        pa[it] = *(const bf16x8*)(Ps + (w * 64 + it * 16 + l16) * 88 + k2 * 32 + quad * 8);
#pragma unroll
      for (int ct = 0; ct < 5; ++ct) {
        bf16x8 vb = *(const bf16x8*)(V_ + (ct * 16 + l16) * 88 + k2 * 32 + quad * 8);
#pragma unroll
        for (int it = 0; it < 4; ++it)
          o[it][ct] = __builtin_amdgcn_mfma_f32_16x16x32_bf16(pa[it], vb, o[it][ct], 0, 0, 0);
      }
    }
  }

#pragma unroll
  for (int it = 0; it < 4; ++it) {
#pragma unroll
    for (int r = 0; r < 4; ++r) {
      float l = lrow[it][r];
      l += __shfl_xor(l, 1, 64);
      l += __shfl_xor(l, 2, 64);
      l += __shfl_xor(l, 4, 64);
      l += __shfl_xor(l, 8, 64);
      float rinv = 1.0f / l;
      long long tok = (long long)c * CHUNK + qt * 256 + w * 64 + it * 16 + quad * 4 + r;
#pragma unroll
      for (int ct = 0; ct < 5; ++ct)
        attn[tok * HID + h * HD + ct * 16 + l16] = (bf16)(o[it][ct][r] * rinv);
    }
  }
}

// ---------------------------------------------------------------------------
extern "C" void kernel_launch(void* const* d_in, const int* in_sizes, int n_in,
                              void* d_out, int out_size, void* d_ws,
                              size_t ws_size, hipStream_t stream) {
  const float* x = (const float*)d_in[0];
  const float* cosp = (const float*)d_in[2];
  const float* sinp = (const float*)d_in[3];
  const float* wqkv = (const float*)d_in[4];
  const float* bqkv = (const float*)d_in[5];
  const float* wproj = (const float*)d_in[6];
  const float* bproj = (const float*)d_in[7];
  bf16* ws = (bf16*)d_ws;
  float* out = (float*)d_out;

  convert_kernel<<<35072, 256, 0, stream>>>(x, wqkv, wproj, ws);
  gemm_bt_kernel<0><<<dim3(64, 15), 512, 0, stream>>>(
      ws + OFF_XB, ws + OFF_WQKV, bqkv, ws, nullptr);
  rope_kernel<<<10240, 256, 0, stream>>>(cosp, sinp, ws);
  attn_kernel<<<dim3(256, 4), 256, 0, stream>>>(ws);
  gemm_bt_kernel<1><<<dim3(64, 5), 512, 0, stream>>>(
      ws + OFF_ATTN, ws + OFF_WPROJ, bproj, ws, out);
}

// Round 2
// 755.792 us; speedup vs baseline: 1.0145x; 1.0145x over previous
//
#include <hip/hip_runtime.h>
#include <cstdint>

typedef __bf16 bf16;
typedef bf16 bf16x8 __attribute__((ext_vector_type(8)));
typedef float f32x4 __attribute__((ext_vector_type(4)));

#define S_LEN   16384
#define HID     1280
#define NHEAD   16
#define HD      80
#define HDP     96
#define CHUNK   1024
#define NCHUNKS 16

// workspace element offsets (bf16 elements)
#define OFF_XB     0LL           // x bf16            [16384][1280]
#define OFF_WQKV   20971520LL    // w_qkv bf16        [3840][1280]
#define OFF_WPROJ  25886720LL    // w_proj bf16       [1280][1280]
#define OFF_QPAD   27525120LL    // q bf16 padded     [16384][16][96]
#define OFF_KPAD   52690944LL    // k bf16 padded     [16384][16][96]
#define OFF_VT     77856768LL    // v^T bf16          [16][16][80][1024]
#define OFF_ATTN   98828288LL    // attn out bf16     [16384][1280]

// global -> LDS direct copy, 16 B per lane; lane i lands at base + i*16.
__device__ __forceinline__ void gl_lds16(const void* g, void* l) {
  __builtin_amdgcn_global_load_lds(
      (const __attribute__((address_space(1))) unsigned int*)g,
      (__attribute__((address_space(3))) unsigned int*)l, 16, 0, 0);
}

// ---------------------------------------------------------------------------
// Kernel 1: fp32 -> bf16 conversion + zero-fill of q/k pad dims (80..95)
// ---------------------------------------------------------------------------
__global__ void convert_kernel(const float* __restrict__ x,
                               const float* __restrict__ wqkv,
                               const float* __restrict__ wproj,
                               bf16* __restrict__ ws) {
  const long long N1 = 20971520LL;
  const long long N2 = 4915200LL;
  const long long N3 = 1638400LL;
  const long long N4 = 4194304LL;
  long long i = ((long long)blockIdx.x * 256 + threadIdx.x) << 2;
  if (i < N1) {
    float4 v = *(const float4*)(x + i);
    bf16* o = ws + OFF_XB + i;
    o[0] = (bf16)v.x; o[1] = (bf16)v.y; o[2] = (bf16)v.z; o[3] = (bf16)v.w;
    return;
  }
  i -= N1;
  if (i < N2) {
    float4 v = *(const float4*)(wqkv + i);
    bf16* o = ws + OFF_WQKV + i;
    o[0] = (bf16)v.x; o[1] = (bf16)v.y; o[2] = (bf16)v.z; o[3] = (bf16)v.w;
    return;
  }
  i -= N2;
  if (i < N3) {
    float4 v = *(const float4*)(wproj + i);
    bf16* o = ws + OFF_WPROJ + i;
    o[0] = (bf16)v.x; o[1] = (bf16)v.y; o[2] = (bf16)v.z; o[3] = (bf16)v.w;
    return;
  }
  i -= N3;
  if (i < N4) {
    long long g = i >> 4; int j = (int)(i & 15);
    *(uint2*)(ws + OFF_QPAD + g * HDP + HD + j) = make_uint2(0u, 0u);
    return;
  }
  i -= N4;
  if (i < N4) {
    long long g = i >> 4; int j = (int)(i & 15);
    *(uint2*)(ws + OFF_KPAD + g * HDP + HD + j) = make_uint2(0u, 0u);
    return;
  }
}

// ---------------------------------------------------------------------------
// Kernels 2 & 5: bf16 GEMM C = A @ B^T (+bias), 256x256 tile, BK=32 K-steps,
// 4-parity LDS pipeline:
//   - 512 thr = 8 waves (2M x 4N), wave tile 128x64, acc[8][4].
//   - LDS: 8 granules x 16 KB = 128 KB. granule(T&3, op) = [256 rows][32 k]
//     bf16, 64-B rows. Conflict fix (round-1 post-mortem): fragment read
//     slot = quad ^ ((l16>>2)&3)  -> each 16-consecutive-lane group covers
//     all 16 16-B slots of the 256-B bank window (was 4-way aliased with
//     the old (l16&3) xor). Staging-side inverse: k-group = sl ^ ((tid>>4)&3)
//     on the per-lane GLOBAL address (global_load_lds dest stays linear).
//   - 2 phases per K-step, ONE barrier per phase; ds_reads for phase P+1
//     issued right after phase P's barrier so they overlap P's MFMA via the
//     compiler's counted lgkmcnt (4 or 8 in flight, max 12 < 15).
//   - counted vmcnt once per K-step (phase A): ledger:
//     prologue: A0,B0,A1,B1 (8 ops), vmcnt(4) -> step0 landed.
//     step T phA: +A(T+2)x2 -> 6 in flight, vmcnt(2) retires A,B(T+1).
//     step T phB: +B(T+2)x2 -> 4 in flight, no wait.  T>=38: vmcnt(0) tail.
//   - DMA overwrite distance: stage(T+2) vs readers of T,T+1: parities
//     distinct mod 4 -> no hazard with a single barrier per phase.
// Grid x = M-strip (fast): blocks sharing an A-strip differ by 64 in id ->
// same XCD -> A fetched once per XCD L2.
// ---------------------------------------------------------------------------
__device__ __forceinline__ void gstep(
    int T, const bf16* __restrict__ srcA, const bf16* __restrict__ srcB,
    char* Gb, int wb, int rbA, int rbB, int csw,
    bf16x8 (&aC)[4], bf16x8 (&bC)[4], bf16x8 (&aN)[4], bf16x8 (&bN)[4],
    f32x4 (&acc)[8][4]) {
  bf16x8 aHi[4];
  // ---- phase A: stage A(T+2); vmcnt; barrier; read aHi(T); MFMA lo half ----
  if (T < 38) {
    const bf16* s = srcA + (T + 2) * 32;
    char* d = Gb + (((T + 2) & 3) * 2) * 16384 + wb;
    gl_lds16(s, d);
    gl_lds16(s + 163840, d + 8192);
    asm volatile("s_waitcnt vmcnt(2)");
  } else {
    asm volatile("s_waitcnt vmcnt(0)");
  }
  __builtin_amdgcn_s_barrier();
  __builtin_amdgcn_sched_barrier(0);
  {
    const char* gA = Gb + ((T & 3) * 2) * 16384;
#pragma unroll
    for (int i = 0; i < 4; ++i)
      aHi[i] = *(const bf16x8*)(gA + rbA + (4 + i) * 1024 + csw);
  }
  __builtin_amdgcn_s_setprio(1);
#pragma unroll
  for (int i = 0; i < 4; ++i)
#pragma unroll
    for (int j = 0; j < 4; ++j)
      acc[i][j] = __builtin_amdgcn_mfma_f32_16x16x32_bf16(
          aC[i], bC[j], acc[i][j], 0, 0, 0);
  __builtin_amdgcn_s_setprio(0);
  // ---- phase B: stage B(T+2); barrier; read next-step aLo/bF; MFMA hi ----
  if (T < 38) {
    const bf16* s = srcB + (T + 2) * 32;
    char* d = Gb + (((T + 2) & 3) * 2 + 1) * 16384 + wb;
    gl_lds16(s, d);
    gl_lds16(s + 163840, d + 8192);
  }
  __builtin_amdgcn_s_barrier();
  __builtin_amdgcn_sched_barrier(0);
  {
    const char* gA = Gb + (((T + 1) & 3) * 2) * 16384;
    const char* gB = Gb + (((T + 1) & 3) * 2 + 1) * 16384;
#pragma unroll
    for (int i = 0; i < 4; ++i)
      aN[i] = *(const bf16x8*)(gA + rbA + i * 1024 + csw);
#pragma unroll
    for (int j = 0; j < 4; ++j)
      bN[j] = *(const bf16x8*)(gB + rbB + j * 1024 + csw);
  }
  __builtin_amdgcn_s_setprio(1);
#pragma unroll
  for (int i = 0; i < 4; ++i)
#pragma unroll
    for (int j = 0; j < 4; ++j)
      acc[4 + i][j] = __builtin_amdgcn_mfma_f32_16x16x32_bf16(
          aHi[i], bC[j], acc[4 + i][j], 0, 0, 0);
  __builtin_amdgcn_s_setprio(0);
}

template <int MODE>
__global__ __launch_bounds__(512, 2) void gemm_bt_kernel(
    const bf16* __restrict__ A, const bf16* __restrict__ B,
    const float* __restrict__ bias, bf16* __restrict__ ws,
    float* __restrict__ outF) {
  __shared__ __align__(16) bf16 G[8][8192];  // 8 granules x 16 KB

  const int tid = threadIdx.x;
  const int lane = tid & 63;
  const int w = tid >> 6;                 // 0..7
  const int wm = w >> 2, wn = w & 3;      // wave row (0,1) / col (0..3)
  const int quad = lane >> 4, l16 = lane & 15;
  const long long m0 = (long long)blockIdx.x * 256;
  const long long n0 = (long long)blockIdx.y * 256;
  const int wb = w * 1024;                // wave-uniform LDS byte base

  // staging: chunk ci = j*512 + tid; row = ci>>2, slot = ci&3.
  // LDS slot stores k-group (slot ^ ((row>>2)&3)) of its row (inverse of
  // the read swizzle; (row>>2)&3 == (tid>>4)&3 for both j=0 and j=1).
  const int r0 = tid >> 2;
  const int kg = (tid & 3) ^ ((tid >> 4) & 3);
  const long long off0 = (long long)r0 * 1280 + (kg << 3);
  const bf16* srcA = A + m0 * 1280 + off0;   // j=1 source: +128 rows = +163840
  const bf16* srcB = B + n0 * 1280 + off0;

  // fragment read bases (byte): row*64 + swizzled 16-B slot
  const int rbA = (wm * 128 + l16) * 64;
  const int rbB = (wn * 64 + l16) * 64;
  const int csw = (quad ^ ((l16 >> 2) & 3)) << 4;

  char* Gb = (char*)G;
  f32x4 acc[8][4] = {};
  bf16x8 aU[4], bU[4], aV[4], bV[4];

  // ---- prologue: stage steps 0,1 in order A0,B0,A1,B1 ----
  gl_lds16(srcA, Gb + wb);
  gl_lds16(srcA + 163840, Gb + wb + 8192);
  gl_lds16(srcB, Gb + 16384 + wb);
  gl_lds16(srcB + 163840, Gb + 16384 + wb + 8192);
  gl_lds16(srcA + 32, Gb + 32768 + wb);
  gl_lds16(srcA + 32 + 163840, Gb + 32768 + wb + 8192);
  gl_lds16(srcB + 32, Gb + 49152 + wb);
  gl_lds16(srcB + 32 + 163840, Gb + 49152 + wb + 8192);
  asm volatile("s_waitcnt vmcnt(4)");
  __builtin_amdgcn_s_barrier();
  __builtin_amdgcn_sched_barrier(0);
#pragma unroll
  for (int i = 0; i < 4; ++i)
    aU[i] = *(const bf16x8*)(Gb + rbA + i * 1024 + csw);
#pragma unroll
  for (int j = 0; j < 4; ++j)
    bU[j] = *(const bf16x8*)(Gb + 16384 + rbB + j * 1024 + csw);

  for (int T = 0; T < 40; T += 2) {
    gstep(T,     srcA, srcB, Gb, wb, rbA, rbB, csw, aU, bU, aV, bV, acc);
    gstep(T + 1, srcA, srcB, Gb, wb, rbA, rbB, csw, aV, bV, aU, bU, acc);
  }

  // ---- epilogue ----
  if (MODE == 0) {
    bf16* qpad = ws + OFF_QPAD;
    bf16* kpad = ws + OFF_KPAD;
    bf16* vt = ws + OFF_VT;
#pragma unroll
    for (int jt = 0; jt < 4; ++jt) {
      int n = (int)n0 + wn * 64 + jt * 16 + l16;
      float bv = bias[n];
      int part = n / HID;
      int idx = n - part * HID;
      int h = idx / HD;
      int d = idx - h * HD;
#pragma unroll
      for (int it = 0; it < 8; ++it) {
#pragma unroll
        for (int r = 0; r < 4; ++r) {
          long long m = m0 + wm * 128 + it * 16 + quad * 4 + r;
          float v = acc[it][jt][r] + bv;
          if (part == 0) {
            qpad[(m * NHEAD + h) * HDP + d] = (bf16)v;
          } else if (part == 1) {
            kpad[(m * NHEAD + h) * HDP + d] = (bf16)v;
          } else {
            long long c = m >> 10, t2 = m & 1023;
            vt[((c * NHEAD + h) * HD + d) * CHUNK + t2] = (bf16)v;
          }
        }
      }
    }
  } else {
#pragma unroll
    for (int jt = 0; jt < 4; ++jt) {
      int n = (int)n0 + wn * 64 + jt * 16 + l16;
      float bv = bias[n];
#pragma unroll
      for (int it = 0; it < 8; ++it) {
#pragma unroll
        for (int r = 0; r < 4; ++r) {
          long long m = m0 + wm * 128 + it * 16 + quad * 4 + r;
          outF[m * HID + n] = acc[it][jt][r] + bv;
        }
      }
    }
  }
}

// ---------------------------------------------------------------------------
// Kernel 3: RoPE in-place, vectorized bf16x8.
// ---------------------------------------------------------------------------
__global__ void rope_kernel(const float* __restrict__ cosp,
                            const float* __restrict__ sinp,
                            bf16* __restrict__ ws) {
  long long i = (long long)blockIdx.x * 256 + threadIdx.x;
  int g = (int)(i % 5);
  long long r = i / 5;
  int h = (int)(r % NHEAD);
  long long r2 = r / NHEAD;
  int tok = (int)(r2 % S_LEN);
  int isK = (int)(r2 / S_LEN);
  bf16* base = ws + (isK ? OFF_KPAD : OFF_QPAD) + ((long long)tok * NHEAD + h) * HDP;
  bf16x8 a8 = *(const bf16x8*)(base + g * 8);
  bf16x8 b8 = *(const bf16x8*)(base + 40 + g * 8);
  const float* cb = cosp + (long long)tok * HD;
  const float* sb = sinp + (long long)tok * HD;
  bf16x8 oA, oB;
#pragma unroll
  for (int j = 0; j < 8; ++j) {
    float a = (float)a8[j], b = (float)b8[j];
    int d = g * 8 + j;
    oA[j] = (bf16)(a * cb[d] - b * sb[d]);
    oB[j] = (bf16)(b * cb[d + 40] + a * sb[d + 40]);
  }
  *(bf16x8*)(base + g * 8) = oA;
  *(bf16x8*)(base + 40 + g * 8) = oB;
}

// ---------------------------------------------------------------------------
// Kernel 4: flash attention. Q-tile 256 (64 rows/wave, it=4), K-tile 64,
// 4 q-blocks per (chunk,head) -> K/V re-read 4x. Grid x = (c,h) so the 4
// sharers have ids congruent mod 8 -> same XCD L2. Fixed-max softmax;
// double-buffered K/V DMA staging; one barrier per tile.
// LDS 26.6+28.7+45 KB = 100 KB -> 1 block/CU.
// ---------------------------------------------------------------------------
__global__ __launch_bounds__(256, 1) void attn_kernel(bf16* __restrict__ ws) {
  __shared__ __align__(16) bf16 Ks[2][64 * 104];       // 13312 B each
  __shared__ __align__(16) bf16 Vs[2][80 * 88 + 128];  // 14336 B each
  __shared__ __align__(16) bf16 Ps[256 * 88];          // 45056 B
  const int ch = blockIdx.x;
  const int c = ch >> 4, h = ch & 15;
  const int qt = blockIdx.y;
  const int tid = threadIdx.x, lane = tid & 63, w = tid >> 6;
  const int quad = lane >> 4, l16 = lane & 15;

  const bf16* qpad = ws + OFF_QPAD;
  const bf16* kpad = ws + OFF_KPAD;
  const bf16* vt = ws + OFF_VT;
  bf16* attn = ws + OFF_ATTN;

  // --- staging source precompute ---
  const char* kbase =
      (const char*)(kpad + (((long long)c * CHUNK) * NHEAD + h) * HDP);
  const char* ksrc[4];
#pragma unroll
  for (int j = 0; j < 4; ++j) {
    int ci = tid + j * 256;
    int ciq = ci < 832 ? ci : 831;
    int row = ciq / 13;
    int cb = (ciq - row * 13) * 16;
    if (cb >= 192) cb = 0;
    ksrc[j] = kbase + row * 3072 + cb;
  }
  const char* vbase = (const char*)(vt + ((long long)c * NHEAD + h) * HD * CHUNK);
  const char* vsrc[4];
#pragma unroll
  for (int j = 0; j < 4; ++j) {
    int ci = tid + j * 256;
    int row = ci / 11;
    if (row > 79) row = 79;
    int cb = (ci - row * 11) * 16;
    if (cb >= 128) cb = 0;
    vsrc[j] = vbase + row * 2048 + cb;
  }
  const int wb = w * 1024;

  // prologue: stage tile 0 into buffer 0
  {
#pragma unroll
    for (int j = 0; j < 3; ++j)
      gl_lds16(ksrc[j], (char*)Ks[0] + j * 4096 + wb);
    if (tid < 64) gl_lds16(ksrc[3], (char*)Ks[0] + 3 * 4096 + wb);
#pragma unroll
    for (int j = 0; j < 3; ++j)
      gl_lds16(vsrc[j], (char*)Vs[0] + j * 4096 + wb);
    if (tid < 128) gl_lds16(vsrc[3], (char*)Vs[0] + 3 * 4096 + wb);
  }

  // --- Q fragments, pre-scaled (overlaps the prologue DMA) ---
  const float scale = 0.111803398875f;  // 1/sqrt(80)
  bf16x8 qf[4][3];
#pragma unroll
  for (int it = 0; it < 4; ++it) {
    long long tok = (long long)c * CHUNK + qt * 256 + w * 64 + it * 16 + l16;
    const bf16* qrow = qpad + (tok * NHEAD + h) * HDP;
#pragma unroll
    for (int ks = 0; ks < 3; ++ks) {
      bf16x8 t = *(const bf16x8*)(qrow + ks * 32 + quad * 8);
#pragma unroll
      for (int j = 0; j < 8; ++j) t[j] = (bf16)((float)t[j] * scale);
      qf[it][ks] = t;
    }
  }

  f32x4 o[4][5] = {};
  float lrow[4][4] = {};

  for (int t = 0; t < 16; ++t) {
    const int cur = t & 1;
    __syncthreads();
    if (t + 1 < 16) {
      const int kadv = (t + 1) * 64 * 3072;
      const int vadv = (t + 1) * 64 * 2;
#pragma unroll
      for (int j = 0; j < 3; ++j)
        gl_lds16(ksrc[j] + kadv, (char*)Ks[cur ^ 1] + j * 4096 + wb);
      if (tid < 64) gl_lds16(ksrc[3] + kadv, (char*)Ks[cur ^ 1] + 3 * 4096 + wb);
#pragma unroll
      for (int j = 0; j < 3; ++j)
        gl_lds16(vsrc[j] + vadv, (char*)Vs[cur ^ 1] + j * 4096 + wb);
      if (tid < 128) gl_lds16(vsrc[3] + vadv, (char*)Vs[cur ^ 1] + 3 * 4096 + wb);
    }
    const bf16* K_ = Ks[cur];
    const bf16* V_ = Vs[cur];

#pragma unroll
    for (int jt = 0; jt < 4; ++jt) {
      bf16x8 kb[3];
#pragma unroll
      for (int ks = 0; ks < 3; ++ks)
        kb[ks] = *(const bf16x8*)(K_ + (jt * 16 + l16) * 104 + ks * 32 + quad * 8);
#pragma unroll
      for (int it = 0; it < 4; ++it) {
        f32x4 z = {};
#pragma unroll
        for (int ks = 0; ks < 3; ++ks)
          z = __builtin_amdgcn_mfma_f32_16x16x32_bf16(qf[it][ks], kb[ks], z, 0, 0, 0);
#pragma unroll
        for (int r = 0; r < 4; ++r) {
          float p2 = __expf(z[r]);
          lrow[it][r] += p2;
          Ps[(w * 64 + it * 16 + quad * 4 + r) * 88 + jt * 16 + l16] = (bf16)p2;
        }
      }
    }

#pragma unroll
    for (int k2 = 0; k2 < 2; ++k2) {
      bf16x8 pa[4];
#pragma unroll
      for (int it = 0; it < 4; ++it)
        pa[it] = *(const bf16x8*)(Ps + (w * 64 + it * 16 + l16) * 88 + k2 * 32 + quad * 8);
#pragma unroll
      for (int ct = 0; ct < 5; ++ct) {
        bf16x8 vb = *(const bf16x8*)(V_ + (ct * 16 + l16) * 88 + k2 * 32 + quad * 8);
#pragma unroll
        for (int it = 0; it < 4; ++it)
          o[it][ct] = __builtin_amdgcn_mfma_f32_16x16x32_bf16(pa[it], vb, o[it][ct], 0, 0, 0);
      }
    }
  }

#pragma unroll
  for (int it = 0; it < 4; ++it) {
#pragma unroll
    for (int r = 0; r < 4; ++r) {
      float l = lrow[it][r];
      l += __shfl_xor(l, 1, 64);
      l += __shfl_xor(l, 2, 64);
      l += __shfl_xor(l, 4, 64);
      l += __shfl_xor(l, 8, 64);
      float rinv = 1.0f / l;
      long long tok = (long long)c * CHUNK + qt * 256 + w * 64 + it * 16 + quad * 4 + r;
#pragma unroll
      for (int ct = 0; ct < 5; ++ct)
        attn[tok * HID + h * HD + ct * 16 + l16] = (bf16)(o[it][ct][r] * rinv);
    }
  }
}

// ---------------------------------------------------------------------------
extern "C" void kernel_launch(void* const* d_in, const int* in_sizes, int n_in,
                              void* d_out, int out_size, void* d_ws,
                              size_t ws_size, hipStream_t stream) {
  const float* x = (const float*)d_in[0];
  const float* cosp = (const float*)d_in[2];
  const float* sinp = (const float*)d_in[3];
  const float* wqkv = (const float*)d_in[4];
  const float* bqkv = (const float*)d_in[5];
  const float* wproj = (const float*)d_in[6];
  const float* bproj = (const float*)d_in[7];
  bf16* ws = (bf16*)d_ws;
  float* out = (float*)d_out;

  convert_kernel<<<35072, 256, 0, stream>>>(x, wqkv, wproj, ws);
  gemm_bt_kernel<0><<<dim3(64, 15), 512, 0, stream>>>(
      ws + OFF_XB, ws + OFF_WQKV, bqkv, ws, nullptr);
  rope_kernel<<<10240, 256, 0, stream>>>(cosp, sinp, ws);
  attn_kernel<<<dim3(256, 4), 256, 0, stream>>>(ws);
  gemm_bt_kernel<1><<<dim3(64, 5), 512, 0, stream>>>(
      ws + OFF_ATTN, ws + OFF_WPROJ, bproj, ws, out);
}

// Round 3
// 752.658 us; speedup vs baseline: 1.0188x; 1.0042x over previous
//
#include <hip/hip_runtime.h>
#include <cstdint>

typedef __bf16 bf16;
typedef bf16 bf16x8 __attribute__((ext_vector_type(8)));
typedef float f32x4 __attribute__((ext_vector_type(4)));

#define S_LEN   16384
#define HID     1280
#define NHEAD   16
#define HD      80
#define HDP     96
#define CHUNK   1024
#define NCHUNKS 16

// workspace element offsets (bf16 elements)
#define OFF_XB     0LL           // x bf16            [16384][1280]
#define OFF_WQKV   20971520LL    // w_qkv bf16        [3840][1280]
#define OFF_WPROJ  25886720LL    // w_proj bf16       [1280][1280]
#define OFF_QPAD   27525120LL    // q bf16 padded     [16384][16][96]
#define OFF_KPAD   52690944LL    // k bf16 padded     [16384][16][96]
#define OFF_VT     77856768LL    // v^T bf16          [16][16][80][1024]
#define OFF_ATTN   98828288LL    // attn out bf16     [16384][1280]

// global -> LDS direct copy, 16 B per lane; lane i lands at base + i*16.
__device__ __forceinline__ void gl_lds16(const void* g, void* l) {
  __builtin_amdgcn_global_load_lds(
      (const __attribute__((address_space(1))) unsigned int*)g,
      (__attribute__((address_space(3))) unsigned int*)l, 16, 0, 0);
}

// ---------------------------------------------------------------------------
// Kernel 1: fp32 -> bf16 conversion + zero-fill of q/k pad dims (80..95)
// ---------------------------------------------------------------------------
__global__ void convert_kernel(const float* __restrict__ x,
                               const float* __restrict__ wqkv,
                               const float* __restrict__ wproj,
                               bf16* __restrict__ ws) {
  const long long N1 = 20971520LL;
  const long long N2 = 4915200LL;
  const long long N3 = 1638400LL;
  const long long N4 = 4194304LL;
  long long i = ((long long)blockIdx.x * 256 + threadIdx.x) << 2;
  if (i < N1) {
    float4 v = *(const float4*)(x + i);
    bf16* o = ws + OFF_XB + i;
    o[0] = (bf16)v.x; o[1] = (bf16)v.y; o[2] = (bf16)v.z; o[3] = (bf16)v.w;
    return;
  }
  i -= N1;
  if (i < N2) {
    float4 v = *(const float4*)(wqkv + i);
    bf16* o = ws + OFF_WQKV + i;
    o[0] = (bf16)v.x; o[1] = (bf16)v.y; o[2] = (bf16)v.z; o[3] = (bf16)v.w;
    return;
  }
  i -= N2;
  if (i < N3) {
    float4 v = *(const float4*)(wproj + i);
    bf16* o = ws + OFF_WPROJ + i;
    o[0] = (bf16)v.x; o[1] = (bf16)v.y; o[2] = (bf16)v.z; o[3] = (bf16)v.w;
    return;
  }
  i -= N3;
  if (i < N4) {
    long long g = i >> 4; int j = (int)(i & 15);
    *(uint2*)(ws + OFF_QPAD + g * HDP + HD + j) = make_uint2(0u, 0u);
    return;
  }
  i -= N4;
  if (i < N4) {
    long long g = i >> 4; int j = (int)(i & 15);
    *(uint2*)(ws + OFF_KPAD + g * HDP + HD + j) = make_uint2(0u, 0u);
    return;
  }
}

// ---------------------------------------------------------------------------
// Kernels 2 & 5: bf16 GEMM C = A @ B^T (+bias), 256x256 tile, BK=32 K-steps,
// MINIMUM-SYNC pipeline (round-3): ONE barrier per K-step.
//   - 512 thr = 8 waves (2M x 4N), wave tile 128x64, acc[8][4].
//   - LDS: 8 granules x 16 KB = 128 KB, 4 parities x {A,B}.
//   - Per step T: {stage granules(T+2) [4 gl_lds]; vmcnt(4) -> retires every
//     wave's (T+1) DMA; s_barrier; sched_barrier; ds_read ALL 12 fragments
//     of step T+1; 32 MFMA on step T's register operands}.  Reads are a full
//     step (~1500+ cyc) ahead of use, DMA 2 steps ahead -> all waits ~0;
//     read-drain overlaps MFMA issue inside the unfenced region.
//   - Hazards (4 parities): stage(T+2) overwrites data last read at step
//     T-2 (>=2 barriers earlier); reads(T+1) follow the barrier at which
//     every wave has retired its (T+1) DMA slice via vmcnt(4).  Tail: T>=38
//     stages nothing and drains with vmcnt(0); T=39's prefetch is dead.
//   - Fragment-read swizzle: slot = quad ^ ((l16>>2)&3): each octet of
//     lanes covers 8 distinct 16-B bank slots (conflict-free); staging-side
//     inverse on the per-lane GLOBAL address (LDS dest stays linear).
// Grid x = M-strip (fast): blocks sharing an A-strip have ids congruent
// mod 8 -> same XCD L2.
// ---------------------------------------------------------------------------
__device__ __forceinline__ void gstep2(
    int T, const bf16* __restrict__ srcA, const bf16* __restrict__ srcB,
    char* Gb, int wb, int rbA, int rbB, int csw,
    bf16x8 (&aC)[8], bf16x8 (&bC)[4],   // step-T operands (consumed)
    bf16x8 (&aN)[8], bf16x8 (&bN)[4],   // step-(T+1) operands (filled)
    f32x4 (&acc)[8][4]) {
  if (T < 38) {
    const bf16* sA = srcA + (T + 2) * 32;
    const bf16* sB = srcB + (T + 2) * 32;
    char* dA = Gb + (((T + 2) & 3) * 2) * 16384 + wb;
    char* dB = Gb + (((T + 2) & 3) * 2 + 1) * 16384 + wb;
    gl_lds16(sA, dA); gl_lds16(sA + 163840, dA + 8192);
    gl_lds16(sB, dB); gl_lds16(sB + 163840, dB + 8192);
    asm volatile("s_waitcnt vmcnt(4)");
  } else {
    asm volatile("s_waitcnt vmcnt(0)");
  }
  __builtin_amdgcn_s_barrier();
  __builtin_amdgcn_sched_barrier(0);
  {
    const char* gA = Gb + (((T + 1) & 3) * 2) * 16384;
    const char* gB = Gb + (((T + 1) & 3) * 2 + 1) * 16384;
#pragma unroll
    for (int i = 0; i < 8; ++i)
      aN[i] = *(const bf16x8*)(gA + rbA + i * 1024 + csw);
#pragma unroll
    for (int j = 0; j < 4; ++j)
      bN[j] = *(const bf16x8*)(gB + rbB + j * 1024 + csw);
  }
  __builtin_amdgcn_s_setprio(1);
#pragma unroll
  for (int i = 0; i < 8; ++i)
#pragma unroll
    for (int j = 0; j < 4; ++j)
      acc[i][j] = __builtin_amdgcn_mfma_f32_16x16x32_bf16(
          aC[i], bC[j], acc[i][j], 0, 0, 0);
  __builtin_amdgcn_s_setprio(0);
}

template <int MODE>
__global__ __launch_bounds__(512, 2) void gemm_bt_kernel(
    const bf16* __restrict__ A, const bf16* __restrict__ B,
    const float* __restrict__ bias, bf16* __restrict__ ws,
    float* __restrict__ outF) {
  __shared__ __align__(16) bf16 G[8][8192];  // 8 granules x 16 KB

  const int tid = threadIdx.x;
  const int lane = tid & 63;
  const int w = tid >> 6;                 // 0..7
  const int wm = w >> 2, wn = w & 3;      // wave row (0,1) / col (0..3)
  const int quad = lane >> 4, l16 = lane & 15;
  const long long m0 = (long long)blockIdx.x * 256;
  const long long n0 = (long long)blockIdx.y * 256;
  const int wb = w * 1024;                // wave-uniform LDS byte base

  // staging: chunk ci = j*512 + tid; row = ci>>2, slot = ci&3.
  // LDS slot stores k-group (slot ^ ((row>>2)&3)) of its row (inverse of
  // the read swizzle; (row>>2)&3 == (tid>>4)&3 for both j=0 and j=1).
  const int r0 = tid >> 2;
  const int kg = (tid & 3) ^ ((tid >> 4) & 3);
  const long long off0 = (long long)r0 * 1280 + (kg << 3);
  const bf16* srcA = A + m0 * 1280 + off0;   // j=1 source: +128 rows = +163840
  const bf16* srcB = B + n0 * 1280 + off0;

  // fragment read bases (byte): row*64 + swizzled 16-B slot
  const int rbA = (wm * 128 + l16) * 64;
  const int rbB = (wn * 64 + l16) * 64;
  const int csw = (quad ^ ((l16 >> 2) & 3)) << 4;

  char* Gb = (char*)G;
  f32x4 acc[8][4] = {};
  bf16x8 aU[8], bU[4], aV[8], bV[4];

  // ---- prologue: stage steps 0,1 (order A0,B0,A1,B1) ----
  gl_lds16(srcA, Gb + wb);
  gl_lds16(srcA + 163840, Gb + wb + 8192);
  gl_lds16(srcB, Gb + 16384 + wb);
  gl_lds16(srcB + 163840, Gb + 16384 + wb + 8192);
  gl_lds16(srcA + 32, Gb + 32768 + wb);
  gl_lds16(srcA + 32 + 163840, Gb + 32768 + wb + 8192);
  gl_lds16(srcB + 32, Gb + 49152 + wb);
  gl_lds16(srcB + 32 + 163840, Gb + 49152 + wb + 8192);
  asm volatile("s_waitcnt vmcnt(4)");
  __builtin_amdgcn_s_barrier();
  __builtin_amdgcn_sched_barrier(0);
#pragma unroll
  for (int i = 0; i < 8; ++i)
    aU[i] = *(const bf16x8*)(Gb + rbA + i * 1024 + csw);
#pragma unroll
  for (int j = 0; j < 4; ++j)
    bU[j] = *(const bf16x8*)(Gb + 16384 + rbB + j * 1024 + csw);

  for (int T = 0; T < 40; T += 2) {
    gstep2(T,     srcA, srcB, Gb, wb, rbA, rbB, csw, aU, bU, aV, bV, acc);
    gstep2(T + 1, srcA, srcB, Gb, wb, rbA, rbB, csw, aV, bV, aU, bU, acc);
  }

  // ---- epilogue ----
  if (MODE == 0) {
    bf16* qpad = ws + OFF_QPAD;
    bf16* kpad = ws + OFF_KPAD;
    bf16* vt = ws + OFF_VT;
#pragma unroll
    for (int jt = 0; jt < 4; ++jt) {
      int n = (int)n0 + wn * 64 + jt * 16 + l16;
      float bv = bias[n];
      int part = n / HID;
      int idx = n - part * HID;
      int h = idx / HD;
      int d = idx - h * HD;
#pragma unroll
      for (int it = 0; it < 8; ++it) {
#pragma unroll
        for (int r = 0; r < 4; ++r) {
          long long m = m0 + wm * 128 + it * 16 + quad * 4 + r;
          float v = acc[it][jt][r] + bv;
          if (part == 0) {
            qpad[(m * NHEAD + h) * HDP + d] = (bf16)v;
          } else if (part == 1) {
            kpad[(m * NHEAD + h) * HDP + d] = (bf16)v;
          } else {
            long long c = m >> 10, t2 = m & 1023;
            vt[((c * NHEAD + h) * HD + d) * CHUNK + t2] = (bf16)v;
          }
        }
      }
    }
  } else {
#pragma unroll
    for (int jt = 0; jt < 4; ++jt) {
      int n = (int)n0 + wn * 64 + jt * 16 + l16;
      float bv = bias[n];
#pragma unroll
      for (int it = 0; it < 8; ++it) {
#pragma unroll
        for (int r = 0; r < 4; ++r) {
          long long m = m0 + wm * 128 + it * 16 + quad * 4 + r;
          outF[m * HID + n] = acc[it][jt][r] + bv;
        }
      }
    }
  }
}

// ---------------------------------------------------------------------------
// Kernel 3: RoPE in-place, vectorized bf16x8.
// ---------------------------------------------------------------------------
__global__ void rope_kernel(const float* __restrict__ cosp,
                            const float* __restrict__ sinp,
                            bf16* __restrict__ ws) {
  long long i = (long long)blockIdx.x * 256 + threadIdx.x;
  int g = (int)(i % 5);
  long long r = i / 5;
  int h = (int)(r % NHEAD);
  long long r2 = r / NHEAD;
  int tok = (int)(r2 % S_LEN);
  int isK = (int)(r2 / S_LEN);
  bf16* base = ws + (isK ? OFF_KPAD : OFF_QPAD) + ((long long)tok * NHEAD + h) * HDP;
  bf16x8 a8 = *(const bf16x8*)(base + g * 8);
  bf16x8 b8 = *(const bf16x8*)(base + 40 + g * 8);
  const float* cb = cosp + (long long)tok * HD;
  const float* sb = sinp + (long long)tok * HD;
  bf16x8 oA, oB;
#pragma unroll
  for (int j = 0; j < 8; ++j) {
    float a = (float)a8[j], b = (float)b8[j];
    int d = g * 8 + j;
    oA[j] = (bf16)(a * cb[d] - b * sb[d]);
    oB[j] = (bf16)(b * cb[d + 40] + a * sb[d + 40]);
  }
  *(bf16x8*)(base + g * 8) = oA;
  *(bf16x8*)(base + 40 + g * 8) = oB;
}

// ---------------------------------------------------------------------------
// Kernel 4: flash attention. Q-tile 256 (64 rows/wave, it=4), K-tile 64,
// 4 q-blocks per (chunk,head) -> K/V re-read 4x. Grid x = (c,h) so the 4
// sharers have ids congruent mod 8 -> same XCD L2. Fixed-max softmax;
// double-buffered K/V DMA staging; one barrier per tile.
// LDS 26.6+28.7+45 KB = 100 KB -> 1 block/CU.
// ---------------------------------------------------------------------------
__global__ __launch_bounds__(256, 1) void attn_kernel(bf16* __restrict__ ws) {
  __shared__ __align__(16) bf16 Ks[2][64 * 104];       // 13312 B each
  __shared__ __align__(16) bf16 Vs[2][80 * 88 + 128];  // 14336 B each
  __shared__ __align__(16) bf16 Ps[256 * 88];          // 45056 B
  const int ch = blockIdx.x;
  const int c = ch >> 4, h = ch & 15;
  const int qt = blockIdx.y;
  const int tid = threadIdx.x, lane = tid & 63, w = tid >> 6;
  const int quad = lane >> 4, l16 = lane & 15;

  const bf16* qpad = ws + OFF_QPAD;
  const bf16* kpad = ws + OFF_KPAD;
  const bf16* vt = ws + OFF_VT;
  bf16* attn = ws + OFF_ATTN;

  // --- staging source precompute ---
  const char* kbase =
      (const char*)(kpad + (((long long)c * CHUNK) * NHEAD + h) * HDP);
  const char* ksrc[4];
#pragma unroll
  for (int j = 0; j < 4; ++j) {
    int ci = tid + j * 256;
    int ciq = ci < 832 ? ci : 831;
    int row = ciq / 13;
    int cb = (ciq - row * 13) * 16;
    if (cb >= 192) cb = 0;
    ksrc[j] = kbase + row * 3072 + cb;
  }
  const char* vbase = (const char*)(vt + ((long long)c * NHEAD + h) * HD * CHUNK);
  const char* vsrc[4];
#pragma unroll
  for (int j = 0; j < 4; ++j) {
    int ci = tid + j * 256;
    int row = ci / 11;
    if (row > 79) row = 79;
    int cb = (ci - row * 11) * 16;
    if (cb >= 128) cb = 0;
    vsrc[j] = vbase + row * 2048 + cb;
  }
  const int wb = w * 1024;

  // prologue: stage tile 0 into buffer 0
  {
#pragma unroll
    for (int j = 0; j < 3; ++j)
      gl_lds16(ksrc[j], (char*)Ks[0] + j * 4096 + wb);
    if (tid < 64) gl_lds16(ksrc[3], (char*)Ks[0] + 3 * 4096 + wb);
#pragma unroll
    for (int j = 0; j < 3; ++j)
      gl_lds16(vsrc[j], (char*)Vs[0] + j * 4096 + wb);
    if (tid < 128) gl_lds16(vsrc[3], (char*)Vs[0] + 3 * 4096 + wb);
  }

  // --- Q fragments, pre-scaled (overlaps the prologue DMA) ---
  const float scale = 0.111803398875f;  // 1/sqrt(80)
  bf16x8 qf[4][3];
#pragma unroll
  for (int it = 0; it < 4; ++it) {
    long long tok = (long long)c * CHUNK + qt * 256 + w * 64 + it * 16 + l16;
    const bf16* qrow = qpad + (tok * NHEAD + h) * HDP;
#pragma unroll
    for (int ks = 0; ks < 3; ++ks) {
      bf16x8 t = *(const bf16x8*)(qrow + ks * 32 + quad * 8);
#pragma unroll
      for (int j = 0; j < 8; ++j) t[j] = (bf16)((float)t[j] * scale);
      qf[it][ks] = t;
    }
  }

  f32x4 o[4][5] = {};
  float lrow[4][4] = {};

  for (int t = 0; t < 16; ++t) {
    const int cur = t & 1;
    __syncthreads();
    if (t + 1 < 16) {
      const int kadv = (t + 1) * 64 * 3072;
      const int vadv = (t + 1) * 64 * 2;
#pragma unroll
      for (int j = 0; j < 3; ++j)
        gl_lds16(ksrc[j] + kadv, (char*)Ks[cur ^ 1] + j * 4096 + wb);
      if (tid < 64) gl_lds16(ksrc[3] + kadv, (char*)Ks[cur ^ 1] + 3 * 4096 + wb);
#pragma unroll
      for (int j = 0; j < 3; ++j)
        gl_lds16(vsrc[j] + vadv, (char*)Vs[cur ^ 1] + j * 4096 + wb);
      if (tid < 128) gl_lds16(vsrc[3] + vadv, (char*)Vs[cur ^ 1] + 3 * 4096 + wb);
    }
    const bf16* K_ = Ks[cur];
    const bf16* V_ = Vs[cur];

#pragma unroll
    for (int jt = 0; jt < 4; ++jt) {
      bf16x8 kb[3];
#pragma unroll
      for (int ks = 0; ks < 3; ++ks)
        kb[ks] = *(const bf16x8*)(K_ + (jt * 16 + l16) * 104 + ks * 32 + quad * 8);
#pragma unroll
      for (int it = 0; it < 4; ++it) {
        f32x4 z = {};
#pragma unroll
        for (int ks = 0; ks < 3; ++ks)
          z = __builtin_amdgcn_mfma_f32_16x16x32_bf16(qf[it][ks], kb[ks], z, 0, 0, 0);
#pragma unroll
        for (int r = 0; r < 4; ++r) {
          float p2 = __expf(z[r]);
          lrow[it][r] += p2;
          Ps[(w * 64 + it * 16 + quad * 4 + r) * 88 + jt * 16 + l16] = (bf16)p2;
        }
      }
    }

#pragma unroll
    for (int k2 = 0; k2 < 2; ++k2) {
      bf16x8 pa[4];
#pragma unroll
      for (int it = 0; it < 4; ++it)
        pa[it] = *(const bf16x8*)(Ps + (w * 64 + it * 16 + l16) * 88 + k2 * 32 + quad * 8);
#pragma unroll
      for (int ct = 0; ct < 5; ++ct) {
        bf16x8 vb = *(const bf16x8*)(V_ + (ct * 16 + l16) * 88 + k2 * 32 + quad * 8);
#pragma unroll
        for (int it = 0; it < 4; ++it)
          o[it][ct] = __builtin_amdgcn_mfma_f32_16x16x32_bf16(pa[it], vb, o[it][ct], 0, 0, 0);
      }
    }
  }

#pragma unroll
  for (int it = 0; it < 4; ++it) {
#pragma unroll
    for (int r = 0; r < 4; ++r) {
      float l = lrow[it][r];
      l += __shfl_xor(l, 1, 64);
      l += __shfl_xor(l, 2, 64);
      l += __shfl_xor(l, 4, 64);
      l += __shfl_xor(l, 8, 64);
      float rinv = 1.0f / l;
      long long tok = (long long)c * CHUNK + qt * 256 + w * 64 + it * 16 + quad * 4 + r;
#pragma unroll
      for (int ct = 0; ct < 5; ++ct)
        attn[tok * HID + h * HD + ct * 16 + l16] = (bf16)(o[it][ct][r] * rinv);
    }
  }
}

// ---------------------------------------------------------------------------
extern "C" void kernel_launch(void* const* d_in, const int* in_sizes, int n_in,
                              void* d_out, int out_size, void* d_ws,
                              size_t ws_size, hipStream_t stream) {
  const float* x = (const float*)d_in[0];
  const float* cosp = (const float*)d_in[2];
  const float* sinp = (const float*)d_in[3];
  const float* wqkv = (const float*)d_in[4];
  const float* bqkv = (const float*)d_in[5];
  const float* wproj = (const float*)d_in[6];
  const float* bproj = (const float*)d_in[7];
  bf16* ws = (bf16*)d_ws;
  float* out = (float*)d_out;

  convert_kernel<<<35072, 256, 0, stream>>>(x, wqkv, wproj, ws);
  gemm_bt_kernel<0><<<dim3(64, 15), 512, 0, stream>>>(
      ws + OFF_XB, ws + OFF_WQKV, bqkv, ws, nullptr);
  rope_kernel<<<10240, 256, 0, stream>>>(cosp, sinp, ws);
  attn_kernel<<<dim3(256, 4), 256, 0, stream>>>(ws);
  gemm_bt_kernel<1><<<dim3(64, 5), 512, 0, stream>>>(
      ws + OFF_ATTN, ws + OFF_WPROJ, bproj, ws, out);
}

// Round 4
// 711.367 us; speedup vs baseline: 1.0779x; 1.0580x over previous
//
#include <hip/hip_runtime.h>
#include <cstdint>

typedef __bf16 bf16;
typedef bf16 bf16x8 __attribute__((ext_vector_type(8)));
typedef float f32x4 __attribute__((ext_vector_type(4)));

#define S_LEN   16384
#define HID     1280
#define NHEAD   16
#define HD      80
#define HDP     96
#define CHUNK   1024
#define NCHUNKS 16

// workspace element offsets (bf16 elements)
#define OFF_XB     0LL           // x bf16            [16384][1280]
#define OFF_WQKV   20971520LL    // w_qkv bf16        [3840][1280]
#define OFF_WPROJ  25886720LL    // w_proj bf16       [1280][1280]
#define OFF_QPAD   27525120LL    // q bf16 padded     [16384][16][96]
#define OFF_KPAD   52690944LL    // k bf16 padded     [16384][16][96]
#define OFF_VT     77856768LL    // v^T bf16          [16][16][80][1024]
#define OFF_ATTN   98828288LL    // attn out bf16     [16384][1280]

// global -> LDS direct copy, 16 B per lane; lane i lands at base + i*16.
__device__ __forceinline__ void gl_lds16(const void* g, void* l) {
  __builtin_amdgcn_global_load_lds(
      (const __attribute__((address_space(1))) unsigned int*)g,
      (__attribute__((address_space(3))) unsigned int*)l, 16, 0, 0);
}

// ---------------------------------------------------------------------------
// Kernel 1: fp32 -> bf16 conversion + zero-fill of q/k pad dims (80..95)
// ---------------------------------------------------------------------------
__global__ void convert_kernel(const float* __restrict__ x,
                               const float* __restrict__ wqkv,
                               const float* __restrict__ wproj,
                               bf16* __restrict__ ws) {
  const long long N1 = 20971520LL;
  const long long N2 = 4915200LL;
  const long long N3 = 1638400LL;
  const long long N4 = 4194304LL;
  long long i = ((long long)blockIdx.x * 256 + threadIdx.x) << 2;
  if (i < N1) {
    float4 v = *(const float4*)(x + i);
    bf16* o = ws + OFF_XB + i;
    o[0] = (bf16)v.x; o[1] = (bf16)v.y; o[2] = (bf16)v.z; o[3] = (bf16)v.w;
    return;
  }
  i -= N1;
  if (i < N2) {
    float4 v = *(const float4*)(wqkv + i);
    bf16* o = ws + OFF_WQKV + i;
    o[0] = (bf16)v.x; o[1] = (bf16)v.y; o[2] = (bf16)v.z; o[3] = (bf16)v.w;
    return;
  }
  i -= N2;
  if (i < N3) {
    float4 v = *(const float4*)(wproj + i);
    bf16* o = ws + OFF_WPROJ + i;
    o[0] = (bf16)v.x; o[1] = (bf16)v.y; o[2] = (bf16)v.z; o[3] = (bf16)v.w;
    return;
  }
  i -= N3;
  if (i < N4) {
    long long g = i >> 4; int j = (int)(i & 15);
    *(uint2*)(ws + OFF_QPAD + g * HDP + HD + j) = make_uint2(0u, 0u);
    return;
  }
  i -= N4;
  if (i < N4) {
    long long g = i >> 4; int j = (int)(i & 15);
    *(uint2*)(ws + OFF_KPAD + g * HDP + HD + j) = make_uint2(0u, 0u);
    return;
  }
}

// ---------------------------------------------------------------------------
// Kernels 2 & 5: bf16 GEMM C = A @ B^T (+bias), 256x256 tile, BK=32 K-steps,
// 4-parity LDS pipeline (round-2 variant — best measured; parked).
// ---------------------------------------------------------------------------
__device__ __forceinline__ void gstep(
    int T, const bf16* __restrict__ srcA, const bf16* __restrict__ srcB,
    char* Gb, int wb, int rbA, int rbB, int csw,
    bf16x8 (&aC)[4], bf16x8 (&bC)[4], bf16x8 (&aN)[4], bf16x8 (&bN)[4],
    f32x4 (&acc)[8][4]) {
  bf16x8 aHi[4];
  // ---- phase A: stage A(T+2); vmcnt; barrier; read aHi(T); MFMA lo half ----
  if (T < 38) {
    const bf16* s = srcA + (T + 2) * 32;
    char* d = Gb + (((T + 2) & 3) * 2) * 16384 + wb;
    gl_lds16(s, d);
    gl_lds16(s + 163840, d + 8192);
    asm volatile("s_waitcnt vmcnt(2)");
  } else {
    asm volatile("s_waitcnt vmcnt(0)");
  }
  __builtin_amdgcn_s_barrier();
  __builtin_amdgcn_sched_barrier(0);
  {
    const char* gA = Gb + ((T & 3) * 2) * 16384;
#pragma unroll
    for (int i = 0; i < 4; ++i)
      aHi[i] = *(const bf16x8*)(gA + rbA + (4 + i) * 1024 + csw);
  }
  __builtin_amdgcn_s_setprio(1);
#pragma unroll
  for (int i = 0; i < 4; ++i)
#pragma unroll
    for (int j = 0; j < 4; ++j)
      acc[i][j] = __builtin_amdgcn_mfma_f32_16x16x32_bf16(
          aC[i], bC[j], acc[i][j], 0, 0, 0);
  __builtin_amdgcn_s_setprio(0);
  // ---- phase B: stage B(T+2); barrier; read next-step aLo/bF; MFMA hi ----
  if (T < 38) {
    const bf16* s = srcB + (T + 2) * 32;
    char* d = Gb + (((T + 2) & 3) * 2 + 1) * 16384 + wb;
    gl_lds16(s, d);
    gl_lds16(s + 163840, d + 8192);
  }
  __builtin_amdgcn_s_barrier();
  __builtin_amdgcn_sched_barrier(0);
  {
    const char* gA = Gb + (((T + 1) & 3) * 2) * 16384;
    const char* gB = Gb + (((T + 1) & 3) * 2 + 1) * 16384;
#pragma unroll
    for (int i = 0; i < 4; ++i)
      aN[i] = *(const bf16x8*)(gA + rbA + i * 1024 + csw);
#pragma unroll
    for (int j = 0; j < 4; ++j)
      bN[j] = *(const bf16x8*)(gB + rbB + j * 1024 + csw);
  }
  __builtin_amdgcn_s_setprio(1);
#pragma unroll
  for (int i = 0; i < 4; ++i)
#pragma unroll
    for (int j = 0; j < 4; ++j)
      acc[4 + i][j] = __builtin_amdgcn_mfma_f32_16x16x32_bf16(
          aHi[i], bC[j], acc[4 + i][j], 0, 0, 0);
  __builtin_amdgcn_s_setprio(0);
}

template <int MODE>
__global__ __launch_bounds__(512, 2) void gemm_bt_kernel(
    const bf16* __restrict__ A, const bf16* __restrict__ B,
    const float* __restrict__ bias, bf16* __restrict__ ws,
    float* __restrict__ outF) {
  __shared__ __align__(16) bf16 G[8][8192];  // 8 granules x 16 KB

  const int tid = threadIdx.x;
  const int lane = tid & 63;
  const int w = tid >> 6;                 // 0..7
  const int wm = w >> 2, wn = w & 3;      // wave row (0,1) / col (0..3)
  const int quad = lane >> 4, l16 = lane & 15;
  const long long m0 = (long long)blockIdx.x * 256;
  const long long n0 = (long long)blockIdx.y * 256;
  const int wb = w * 1024;                // wave-uniform LDS byte base

  const int r0 = tid >> 2;
  const int kg = (tid & 3) ^ ((tid >> 4) & 3);
  const long long off0 = (long long)r0 * 1280 + (kg << 3);
  const bf16* srcA = A + m0 * 1280 + off0;   // j=1 source: +128 rows = +163840
  const bf16* srcB = B + n0 * 1280 + off0;

  const int rbA = (wm * 128 + l16) * 64;
  const int rbB = (wn * 64 + l16) * 64;
  const int csw = (quad ^ ((l16 >> 2) & 3)) << 4;

  char* Gb = (char*)G;
  f32x4 acc[8][4] = {};
  bf16x8 aU[4], bU[4], aV[4], bV[4];

  // ---- prologue: stage steps 0,1 (order A0,B0,A1,B1) ----
  gl_lds16(srcA, Gb + wb);
  gl_lds16(srcA + 163840, Gb + wb + 8192);
  gl_lds16(srcB, Gb + 16384 + wb);
  gl_lds16(srcB + 163840, Gb + 16384 + wb + 8192);
  gl_lds16(srcA + 32, Gb + 32768 + wb);
  gl_lds16(srcA + 32 + 163840, Gb + 32768 + wb + 8192);
  gl_lds16(srcB + 32, Gb + 49152 + wb);
  gl_lds16(srcB + 32 + 163840, Gb + 49152 + wb + 8192);
  asm volatile("s_waitcnt vmcnt(4)");
  __builtin_amdgcn_s_barrier();
  __builtin_amdgcn_sched_barrier(0);
#pragma unroll
  for (int i = 0; i < 4; ++i)
    aU[i] = *(const bf16x8*)(Gb + rbA + i * 1024 + csw);
#pragma unroll
  for (int j = 0; j < 4; ++j)
    bU[j] = *(const bf16x8*)(Gb + 16384 + rbB + j * 1024 + csw);

  for (int T = 0; T < 40; T += 2) {
    gstep(T,     srcA, srcB, Gb, wb, rbA, rbB, csw, aU, bU, aV, bV, acc);
    gstep(T + 1, srcA, srcB, Gb, wb, rbA, rbB, csw, aV, bV, aU, bU, acc);
  }

  // ---- epilogue ----
  if (MODE == 0) {
    bf16* qpad = ws + OFF_QPAD;
    bf16* kpad = ws + OFF_KPAD;
    bf16* vt = ws + OFF_VT;
#pragma unroll
    for (int jt = 0; jt < 4; ++jt) {
      int n = (int)n0 + wn * 64 + jt * 16 + l16;
      float bv = bias[n];
      int part = n / HID;
      int idx = n - part * HID;
      int h = idx / HD;
      int d = idx - h * HD;
#pragma unroll
      for (int it = 0; it < 8; ++it) {
#pragma unroll
        for (int r = 0; r < 4; ++r) {
          long long m = m0 + wm * 128 + it * 16 + quad * 4 + r;
          float v = acc[it][jt][r] + bv;
          if (part == 0) {
            qpad[(m * NHEAD + h) * HDP + d] = (bf16)v;
          } else if (part == 1) {
            kpad[(m * NHEAD + h) * HDP + d] = (bf16)v;
          } else {
            long long c = m >> 10, t2 = m & 1023;
            vt[((c * NHEAD + h) * HD + d) * CHUNK + t2] = (bf16)v;
          }
        }
      }
    }
  } else {
#pragma unroll
    for (int jt = 0; jt < 4; ++jt) {
      int n = (int)n0 + wn * 64 + jt * 16 + l16;
      float bv = bias[n];
#pragma unroll
      for (int it = 0; it < 8; ++it) {
#pragma unroll
        for (int r = 0; r < 4; ++r) {
          long long m = m0 + wm * 128 + it * 16 + quad * 4 + r;
          outF[m * HID + n] = acc[it][jt][r] + bv;
        }
      }
    }
  }
}

// ---------------------------------------------------------------------------
// Kernel 3: RoPE in-place, vectorized bf16x8.
// ---------------------------------------------------------------------------
__global__ void rope_kernel(const float* __restrict__ cosp,
                            const float* __restrict__ sinp,
                            bf16* __restrict__ ws) {
  long long i = (long long)blockIdx.x * 256 + threadIdx.x;
  int g = (int)(i % 5);
  long long r = i / 5;
  int h = (int)(r % NHEAD);
  long long r2 = r / NHEAD;
  int tok = (int)(r2 % S_LEN);
  int isK = (int)(r2 / S_LEN);
  bf16* base = ws + (isK ? OFF_KPAD : OFF_QPAD) + ((long long)tok * NHEAD + h) * HDP;
  bf16x8 a8 = *(const bf16x8*)(base + g * 8);
  bf16x8 b8 = *(const bf16x8*)(base + 40 + g * 8);
  const float* cb = cosp + (long long)tok * HD;
  const float* sb = sinp + (long long)tok * HD;
  bf16x8 oA, oB;
#pragma unroll
  for (int j = 0; j < 8; ++j) {
    float a = (float)a8[j], b = (float)b8[j];
    int d = g * 8 + j;
    oA[j] = (bf16)(a * cb[d] - b * sb[d]);
    oB[j] = (bf16)(b * cb[d + 40] + a * sb[d + 40]);
  }
  *(bf16x8*)(base + g * 8) = oA;
  *(bf16x8*)(base + 40 + g * 8) = oB;
}

// ---------------------------------------------------------------------------
// Kernel 4: flash attention — round-4: 512 threads / 8 waves (was 256/4).
// Diagnosis: 100 KB LDS -> 1 block/CU; at 256 thr that was 1 wave/SIMD =
// zero TLP, every ds_read/MFMA/exp/barrier latency fully exposed (measured
// ~8600 cyc/step vs ~1900 pipe bound). 8 waves = 2 waves/SIMD doubles
// latency-hiding with the same LDS layout, math, and grid. Each wave owns
// 32 Q-rows (it=2). Staging re-indexed for 512 thr: K image 832 chunks
// (j=0 full, j=1 tid<320 = 5 full waves), V image 880 chunks (j=0 full,
// j=1 tid<368, exec-masked tail lanes in wave 5).
// ---------------------------------------------------------------------------
__global__ __launch_bounds__(512, 1) void attn_kernel(bf16* __restrict__ ws) {
  __shared__ __align__(16) bf16 Ks[2][64 * 104];       // 13312 B each
  __shared__ __align__(16) bf16 Vs[2][80 * 88 + 128];  // 14336 B each
  __shared__ __align__(16) bf16 Ps[256 * 88];          // 45056 B
  const int ch = blockIdx.x;
  const int c = ch >> 4, h = ch & 15;
  const int qt = blockIdx.y;
  const int tid = threadIdx.x, lane = tid & 63, w = tid >> 6;
  const int quad = lane >> 4, l16 = lane & 15;

  const bf16* qpad = ws + OFF_QPAD;
  const bf16* kpad = ws + OFF_KPAD;
  const bf16* vt = ws + OFF_VT;
  bf16* attn = ws + OFF_ATTN;

  // --- staging source precompute (chunk ci = j*512 + tid) ---
  const char* kbase =
      (const char*)(kpad + (((long long)c * CHUNK) * NHEAD + h) * HDP);
  const char* ksrc[2];
#pragma unroll
  for (int j = 0; j < 2; ++j) {
    int ci = tid + j * 512;
    int ciq = ci < 832 ? ci : 831;
    int row = ciq / 13;
    int cb = (ciq - row * 13) * 16;
    if (cb >= 192) cb = 0;
    ksrc[j] = kbase + row * 3072 + cb;
  }
  const char* vbase = (const char*)(vt + ((long long)c * NHEAD + h) * HD * CHUNK);
  const char* vsrc[2];
#pragma unroll
  for (int j = 0; j < 2; ++j) {
    int ci = tid + j * 512;
    int row = ci / 11;
    if (row > 79) row = 79;
    int cb = (ci - row * 11) * 16;
    if (cb >= 128) cb = 0;
    vsrc[j] = vbase + row * 2048 + cb;
  }
  const int wb = w * 1024;

  // prologue: stage tile 0 into buffer 0
  {
    gl_lds16(ksrc[0], (char*)Ks[0] + wb);
    if (tid < 320) gl_lds16(ksrc[1], (char*)Ks[0] + 8192 + wb);
    gl_lds16(vsrc[0], (char*)Vs[0] + wb);
    if (tid < 368) gl_lds16(vsrc[1], (char*)Vs[0] + 8192 + wb);
  }

  // --- Q fragments, pre-scaled (overlaps the prologue DMA) ---
  const float scale = 0.111803398875f;  // 1/sqrt(80)
  bf16x8 qf[2][3];
#pragma unroll
  for (int it = 0; it < 2; ++it) {
    long long tok = (long long)c * CHUNK + qt * 256 + w * 32 + it * 16 + l16;
    const bf16* qrow = qpad + (tok * NHEAD + h) * HDP;
#pragma unroll
    for (int ks = 0; ks < 3; ++ks) {
      bf16x8 t = *(const bf16x8*)(qrow + ks * 32 + quad * 8);
#pragma unroll
      for (int j = 0; j < 8; ++j) t[j] = (bf16)((float)t[j] * scale);
      qf[it][ks] = t;
    }
  }

  f32x4 o[2][5] = {};
  float lrow[2][4] = {};

  for (int t = 0; t < 16; ++t) {
    const int cur = t & 1;
    __syncthreads();
    if (t + 1 < 16) {
      const int kadv = (t + 1) * 64 * 3072;
      const int vadv = (t + 1) * 64 * 2;
      gl_lds16(ksrc[0] + kadv, (char*)Ks[cur ^ 1] + wb);
      if (tid < 320) gl_lds16(ksrc[1] + kadv, (char*)Ks[cur ^ 1] + 8192 + wb);
      gl_lds16(vsrc[0] + vadv, (char*)Vs[cur ^ 1] + wb);
      if (tid < 368) gl_lds16(vsrc[1] + vadv, (char*)Vs[cur ^ 1] + 8192 + wb);
    }
    const bf16* K_ = Ks[cur];
    const bf16* V_ = Vs[cur];

    // S = Q K^T, exp, Ps write (wave-private rows w*32..w*32+31)
#pragma unroll
    for (int jt = 0; jt < 4; ++jt) {
      bf16x8 kb[3];
#pragma unroll
      for (int ks = 0; ks < 3; ++ks)
        kb[ks] = *(const bf16x8*)(K_ + (jt * 16 + l16) * 104 + ks * 32 + quad * 8);
#pragma unroll
      for (int it = 0; it < 2; ++it) {
        f32x4 z = {};
#pragma unroll
        for (int ks = 0; ks < 3; ++ks)
          z = __builtin_amdgcn_mfma_f32_16x16x32_bf16(qf[it][ks], kb[ks], z, 0, 0, 0);
#pragma unroll
        for (int r = 0; r < 4; ++r) {
          float p2 = __expf(z[r]);
          lrow[it][r] += p2;
          Ps[(w * 32 + it * 16 + quad * 4 + r) * 88 + jt * 16 + l16] = (bf16)p2;
        }
      }
    }

    // O += P V (Ps same-wave write->read; compiler inserts lgkmcnt wait)
#pragma unroll
    for (int k2 = 0; k2 < 2; ++k2) {
      bf16x8 pa[2];
#pragma unroll
      for (int it = 0; it < 2; ++it)
        pa[it] = *(const bf16x8*)(Ps + (w * 32 + it * 16 + l16) * 88 + k2 * 32 + quad * 8);
#pragma unroll
      for (int ct = 0; ct < 5; ++ct) {
        bf16x8 vb = *(const bf16x8*)(V_ + (ct * 16 + l16) * 88 + k2 * 32 + quad * 8);
#pragma unroll
        for (int it = 0; it < 2; ++it)
          o[it][ct] = __builtin_amdgcn_mfma_f32_16x16x32_bf16(pa[it], vb, o[it][ct], 0, 0, 0);
      }
    }
  }

  // final row-sum reduce (over l16) and write
#pragma unroll
  for (int it = 0; it < 2; ++it) {
#pragma unroll
    for (int r = 0; r < 4; ++r) {
      float l = lrow[it][r];
      l += __shfl_xor(l, 1, 64);
      l += __shfl_xor(l, 2, 64);
      l += __shfl_xor(l, 4, 64);
      l += __shfl_xor(l, 8, 64);
      float rinv = 1.0f / l;
      long long tok = (long long)c * CHUNK + qt * 256 + w * 32 + it * 16 + quad * 4 + r;
#pragma unroll
      for (int ct = 0; ct < 5; ++ct)
        attn[tok * HID + h * HD + ct * 16 + l16] = (bf16)(o[it][ct][r] * rinv);
    }
  }
}

// ---------------------------------------------------------------------------
extern "C" void kernel_launch(void* const* d_in, const int* in_sizes, int n_in,
                              void* d_out, int out_size, void* d_ws,
                              size_t ws_size, hipStream_t stream) {
  const float* x = (const float*)d_in[0];
  const float* cosp = (const float*)d_in[2];
  const float* sinp = (const float*)d_in[3];
  const float* wqkv = (const float*)d_in[4];
  const float* bqkv = (const float*)d_in[5];
  const float* wproj = (const float*)d_in[6];
  const float* bproj = (const float*)d_in[7];
  bf16* ws = (bf16*)d_ws;
  float* out = (float*)d_out;

  convert_kernel<<<35072, 256, 0, stream>>>(x, wqkv, wproj, ws);
  gemm_bt_kernel<0><<<dim3(64, 15), 512, 0, stream>>>(
      ws + OFF_XB, ws + OFF_WQKV, bqkv, ws, nullptr);
  rope_kernel<<<10240, 256, 0, stream>>>(cosp, sinp, ws);
  attn_kernel<<<dim3(256, 4), 512, 0, stream>>>(ws);
  gemm_bt_kernel<1><<<dim3(64, 5), 512, 0, stream>>>(
      ws + OFF_ATTN, ws + OFF_WPROJ, bproj, ws, out);
}

// Round 5
// 702.644 us; speedup vs baseline: 1.0913x; 1.0124x over previous
//
#include <hip/hip_runtime.h>
#include <cstdint>

typedef __bf16 bf16;
typedef bf16 bf16x8 __attribute__((ext_vector_type(8)));
typedef float f32x4 __attribute__((ext_vector_type(4)));

#define S_LEN   16384
#define HID     1280
#define NHEAD   16
#define HD      80
#define HDP     96
#define CHUNK   1024
#define NCHUNKS 16

// workspace element offsets (bf16 elements)
#define OFF_XB     0LL           // x bf16            [16384][1280]
#define OFF_WQKV   20971520LL    // w_qkv bf16        [3840][1280]
#define OFF_WPROJ  25886720LL    // w_proj bf16       [1280][1280]
#define OFF_QPAD   27525120LL    // q bf16 padded     [16384][16][96]
#define OFF_KPAD   52690944LL    // k bf16 padded     [16384][16][96]
#define OFF_VT     77856768LL    // v^T bf16          [16][16][80][1024]
#define OFF_ATTN   98828288LL    // attn out bf16     [16384][1280]

// global -> LDS direct copy, 16 B per lane; lane i lands at base + i*16.
__device__ __forceinline__ void gl_lds16(const void* g, void* l) {
  __builtin_amdgcn_global_load_lds(
      (const __attribute__((address_space(1))) unsigned int*)g,
      (__attribute__((address_space(3))) unsigned int*)l, 16, 0, 0);
}

// ---------------------------------------------------------------------------
// Kernel 1: fp32 -> bf16 conversion + zero-fill of q/k pad dims (80..95)
// ---------------------------------------------------------------------------
__global__ void convert_kernel(const float* __restrict__ x,
                               const float* __restrict__ wqkv,
                               const float* __restrict__ wproj,
                               bf16* __restrict__ ws) {
  const long long N1 = 20971520LL;
  const long long N2 = 4915200LL;
  const long long N3 = 1638400LL;
  const long long N4 = 4194304LL;
  long long i = ((long long)blockIdx.x * 256 + threadIdx.x) << 2;
  if (i < N1) {
    float4 v = *(const float4*)(x + i);
    bf16* o = ws + OFF_XB + i;
    o[0] = (bf16)v.x; o[1] = (bf16)v.y; o[2] = (bf16)v.z; o[3] = (bf16)v.w;
    return;
  }
  i -= N1;
  if (i < N2) {
    float4 v = *(const float4*)(wqkv + i);
    bf16* o = ws + OFF_WQKV + i;
    o[0] = (bf16)v.x; o[1] = (bf16)v.y; o[2] = (bf16)v.z; o[3] = (bf16)v.w;
    return;
  }
  i -= N2;
  if (i < N3) {
    float4 v = *(const float4*)(wproj + i);
    bf16* o = ws + OFF_WPROJ + i;
    o[0] = (bf16)v.x; o[1] = (bf16)v.y; o[2] = (bf16)v.z; o[3] = (bf16)v.w;
    return;
  }
  i -= N3;
  if (i < N4) {
    long long g = i >> 4; int j = (int)(i & 15);
    *(uint2*)(ws + OFF_QPAD + g * HDP + HD + j) = make_uint2(0u, 0u);
    return;
  }
  i -= N4;
  if (i < N4) {
    long long g = i >> 4; int j = (int)(i & 15);
    *(uint2*)(ws + OFF_KPAD + g * HDP + HD + j) = make_uint2(0u, 0u);
    return;
  }
}

// ---------------------------------------------------------------------------
// Kernels 2 & 5: bf16 GEMM C = A @ B^T (+bias) — round-5: 128x128 tile,
// 256 thr / 4 waves, wave-tile 64x64 (acc[4][4]), BK=32, double-buffered
// 32 KB LDS, __launch_bounds__(256,4) (VGPR<=128) -> up to 4 INDEPENDENT
// blocks/CU.  Rationale (rounds 0-3 evidence): barrier-synced waves within
// one block stall together at the staging drain; independent blocks
// interleave freely (m114).  m97-class structure (874 TF at 4k^3 on this
// chip).  Grids: g0 (128,30)=3840 blocks (15 exact CU-rounds), g1
// (128,10)=1280 (kills the old 320-block tail).  blockIdx.x = M-fast:
// blocks sharing an A-strip have ids congruent mod 8 -> same XCD L2.
// LDS layout per buffer: A[128 rows][32k] @0, B[128][32k] @8192 B; 64-B
// rows; 16-B slot swizzle slot = quad ^ ((l16>>2)&3) on reads, inverse
// k-group permutation on the per-lane GLOBAL staging address (LDS dest
// linear, as global_load_lds requires).
// ---------------------------------------------------------------------------
template <int MODE>
__global__ __launch_bounds__(256, 4) void gemm_bt_kernel(
    const bf16* __restrict__ A, const bf16* __restrict__ B,
    const float* __restrict__ bias, bf16* __restrict__ ws,
    float* __restrict__ outF) {
  __shared__ __align__(16) bf16 AB[2][8192];  // 16 KB per buffer

  const int tid = threadIdx.x;
  const int lane = tid & 63;
  const int w = tid >> 6;                 // 0..3
  const int wr = w >> 1, wc = w & 1;      // wave row / col
  const int quad = lane >> 4, l16 = lane & 15;
  const long long m0 = (long long)blockIdx.x * 128;
  const long long n0 = (long long)blockIdx.y * 128;

  // staging: chunk ci = j*256 + tid (j=0,1 per operand); row = ci>>2 (0..127),
  // slot = ci&3.  LDS slot stores k-group (slot ^ ((row>>2)&3)) of its row;
  // (row>>2)&3 == (tid>>4)&3 for both j (row advance 64 keeps &3).
  const int r0 = tid >> 2;
  const int kg = (tid & 3) ^ ((tid >> 4) & 3);
  const long long off0 = (long long)r0 * 1280 + (kg << 3);
  const bf16* srcA = A + m0 * 1280 + off0;   // j=1 source: +64 rows = +81920
  const bf16* srcB = B + n0 * 1280 + off0;

  // fragment read bases (byte): row*64 + swizzled 16-B slot
  const int rbA = (wr * 64 + l16) * 64;
  const int rbB = (wc * 64 + l16) * 64;
  const int csw = (quad ^ ((l16 >> 2) & 3)) << 4;

  f32x4 acc[4][4] = {};

  // prologue: stage step 0 into buffer 0
  {
    char* d = (char*)AB[0] + tid * 16;
    gl_lds16(srcA, d);           gl_lds16(srcA + 81920, d + 4096);
    gl_lds16(srcB, d + 8192);    gl_lds16(srcB + 81920, d + 12288);
  }

  for (int k0 = 0; k0 < 40; ++k0) {
    const int cur = k0 & 1;
    __syncthreads();  // drains vmcnt -> buf[cur] ready; buf[cur^1] free
    if (k0 + 1 < 40) {
      const bf16* sA = srcA + (k0 + 1) * 32;
      const bf16* sB = srcB + (k0 + 1) * 32;
      char* d = (char*)AB[cur ^ 1] + tid * 16;
      gl_lds16(sA, d);           gl_lds16(sA + 81920, d + 4096);
      gl_lds16(sB, d + 8192);    gl_lds16(sB + 81920, d + 12288);
    }
    const char* buf = (const char*)AB[cur];
    bf16x8 af[4], bfr[4];
#pragma unroll
    for (int it = 0; it < 4; ++it)
      af[it] = *(const bf16x8*)(buf + rbA + it * 1024 + csw);
#pragma unroll
    for (int jt = 0; jt < 4; ++jt)
      bfr[jt] = *(const bf16x8*)(buf + 8192 + rbB + jt * 1024 + csw);
#pragma unroll
    for (int it = 0; it < 4; ++it)
#pragma unroll
      for (int jt = 0; jt < 4; ++jt)
        acc[it][jt] = __builtin_amdgcn_mfma_f32_16x16x32_bf16(
            af[it], bfr[jt], acc[it][jt], 0, 0, 0);
  }

  // ---- epilogue ----
  if (MODE == 0) {
    bf16* qpad = ws + OFF_QPAD;
    bf16* kpad = ws + OFF_KPAD;
    bf16* vt = ws + OFF_VT;
#pragma unroll
    for (int jt = 0; jt < 4; ++jt) {
      int n = (int)n0 + wc * 64 + jt * 16 + l16;
      float bv = bias[n];
      int part = n / HID;
      int idx = n - part * HID;
      int h = idx / HD;
      int d = idx - h * HD;
#pragma unroll
      for (int it = 0; it < 4; ++it) {
#pragma unroll
        for (int r = 0; r < 4; ++r) {
          long long m = m0 + wr * 64 + it * 16 + quad * 4 + r;
          float v = acc[it][jt][r] + bv;
          if (part == 0) {
            qpad[(m * NHEAD + h) * HDP + d] = (bf16)v;
          } else if (part == 1) {
            kpad[(m * NHEAD + h) * HDP + d] = (bf16)v;
          } else {
            long long c = m >> 10, t2 = m & 1023;
            vt[((c * NHEAD + h) * HD + d) * CHUNK + t2] = (bf16)v;
          }
        }
      }
    }
  } else {
#pragma unroll
    for (int jt = 0; jt < 4; ++jt) {
      int n = (int)n0 + wc * 64 + jt * 16 + l16;
      float bv = bias[n];
#pragma unroll
      for (int it = 0; it < 4; ++it) {
#pragma unroll
        for (int r = 0; r < 4; ++r) {
          long long m = m0 + wr * 64 + it * 16 + quad * 4 + r;
          outF[m * HID + n] = acc[it][jt][r] + bv;
        }
      }
    }
  }
}

// ---------------------------------------------------------------------------
// Kernel 3: RoPE in-place, vectorized bf16x8.
// ---------------------------------------------------------------------------
__global__ void rope_kernel(const float* __restrict__ cosp,
                            const float* __restrict__ sinp,
                            bf16* __restrict__ ws) {
  long long i = (long long)blockIdx.x * 256 + threadIdx.x;
  int g = (int)(i % 5);
  long long r = i / 5;
  int h = (int)(r % NHEAD);
  long long r2 = r / NHEAD;
  int tok = (int)(r2 % S_LEN);
  int isK = (int)(r2 / S_LEN);
  bf16* base = ws + (isK ? OFF_KPAD : OFF_QPAD) + ((long long)tok * NHEAD + h) * HDP;
  bf16x8 a8 = *(const bf16x8*)(base + g * 8);
  bf16x8 b8 = *(const bf16x8*)(base + 40 + g * 8);
  const float* cb = cosp + (long long)tok * HD;
  const float* sb = sinp + (long long)tok * HD;
  bf16x8 oA, oB;
#pragma unroll
  for (int j = 0; j < 8; ++j) {
    float a = (float)a8[j], b = (float)b8[j];
    int d = g * 8 + j;
    oA[j] = (bf16)(a * cb[d] - b * sb[d]);
    oB[j] = (bf16)(b * cb[d + 40] + a * sb[d + 40]);
  }
  *(bf16x8*)(base + g * 8) = oA;
  *(bf16x8*)(base + 40 + g * 8) = oB;
}

// ---------------------------------------------------------------------------
// Kernel 4: flash attention — 512 threads / 8 waves (round-4 version).
// Each wave owns 32 Q-rows (it=2). K-tile 64, double-buffered DMA staging,
// one barrier per tile. LDS 100 KB -> 1 block/CU, 8 waves = 2/SIMD.
// ---------------------------------------------------------------------------
__global__ __launch_bounds__(512, 1) void attn_kernel(bf16* __restrict__ ws) {
  __shared__ __align__(16) bf16 Ks[2][64 * 104];       // 13312 B each
  __shared__ __align__(16) bf16 Vs[2][80 * 88 + 128];  // 14336 B each
  __shared__ __align__(16) bf16 Ps[256 * 88];          // 45056 B
  const int ch = blockIdx.x;
  const int c = ch >> 4, h = ch & 15;
  const int qt = blockIdx.y;
  const int tid = threadIdx.x, lane = tid & 63, w = tid >> 6;
  const int quad = lane >> 4, l16 = lane & 15;

  const bf16* qpad = ws + OFF_QPAD;
  const bf16* kpad = ws + OFF_KPAD;
  const bf16* vt = ws + OFF_VT;
  bf16* attn = ws + OFF_ATTN;

  // --- staging source precompute (chunk ci = j*512 + tid) ---
  const char* kbase =
      (const char*)(kpad + (((long long)c * CHUNK) * NHEAD + h) * HDP);
  const char* ksrc[2];
#pragma unroll
  for (int j = 0; j < 2; ++j) {
    int ci = tid + j * 512;
    int ciq = ci < 832 ? ci : 831;
    int row = ciq / 13;
    int cb = (ciq - row * 13) * 16;
    if (cb >= 192) cb = 0;
    ksrc[j] = kbase + row * 3072 + cb;
  }
  const char* vbase = (const char*)(vt + ((long long)c * NHEAD + h) * HD * CHUNK);
  const char* vsrc[2];
#pragma unroll
  for (int j = 0; j < 2; ++j) {
    int ci = tid + j * 512;
    int row = ci / 11;
    if (row > 79) row = 79;
    int cb = (ci - row * 11) * 16;
    if (cb >= 128) cb = 0;
    vsrc[j] = vbase + row * 2048 + cb;
  }
  const int wb = w * 1024;

  // prologue: stage tile 0 into buffer 0
  {
    gl_lds16(ksrc[0], (char*)Ks[0] + wb);
    if (tid < 320) gl_lds16(ksrc[1], (char*)Ks[0] + 8192 + wb);
    gl_lds16(vsrc[0], (char*)Vs[0] + wb);
    if (tid < 368) gl_lds16(vsrc[1], (char*)Vs[0] + 8192 + wb);
  }

  // --- Q fragments, pre-scaled (overlaps the prologue DMA) ---
  const float scale = 0.111803398875f;  // 1/sqrt(80)
  bf16x8 qf[2][3];
#pragma unroll
  for (int it = 0; it < 2; ++it) {
    long long tok = (long long)c * CHUNK + qt * 256 + w * 32 + it * 16 + l16;
    const bf16* qrow = qpad + (tok * NHEAD + h) * HDP;
#pragma unroll
    for (int ks = 0; ks < 3; ++ks) {
      bf16x8 t = *(const bf16x8*)(qrow + ks * 32 + quad * 8);
#pragma unroll
      for (int j = 0; j < 8; ++j) t[j] = (bf16)((float)t[j] * scale);
      qf[it][ks] = t;
    }
  }

  f32x4 o[2][5] = {};
  float lrow[2][4] = {};

  for (int t = 0; t < 16; ++t) {
    const int cur = t & 1;
    __syncthreads();
    if (t + 1 < 16) {
      const int kadv = (t + 1) * 64 * 3072;
      const int vadv = (t + 1) * 64 * 2;
      gl_lds16(ksrc[0] + kadv, (char*)Ks[cur ^ 1] + wb);
      if (tid < 320) gl_lds16(ksrc[1] + kadv, (char*)Ks[cur ^ 1] + 8192 + wb);
      gl_lds16(vsrc[0] + vadv, (char*)Vs[cur ^ 1] + wb);
      if (tid < 368) gl_lds16(vsrc[1] + vadv, (char*)Vs[cur ^ 1] + 8192 + wb);
    }
    const bf16* K_ = Ks[cur];
    const bf16* V_ = Vs[cur];

    // S = Q K^T, exp, Ps write (wave-private rows w*32..w*32+31)
#pragma unroll
    for (int jt = 0; jt < 4; ++jt) {
      bf16x8 kb[3];
#pragma unroll
      for (int ks = 0; ks < 3; ++ks)
        kb[ks] = *(const bf16x8*)(K_ + (jt * 16 + l16) * 104 + ks * 32 + quad * 8);
#pragma unroll
      for (int it = 0; it < 2; ++it) {
        f32x4 z = {};
#pragma unroll
        for (int ks = 0; ks < 3; ++ks)
          z = __builtin_amdgcn_mfma_f32_16x16x32_bf16(qf[it][ks], kb[ks], z, 0, 0, 0);
#pragma unroll
        for (int r = 0; r < 4; ++r) {
          float p2 = __expf(z[r]);
          lrow[it][r] += p2;
          Ps[(w * 32 + it * 16 + quad * 4 + r) * 88 + jt * 16 + l16] = (bf16)p2;
        }
      }
    }

    // O += P V (Ps same-wave write->read; compiler inserts lgkmcnt wait)
#pragma unroll
    for (int k2 = 0; k2 < 2; ++k2) {
      bf16x8 pa[2];
#pragma unroll
      for (int it = 0; it < 2; ++it)
        pa[it] = *(const bf16x8*)(Ps + (w * 32 + it * 16 + l16) * 88 + k2 * 32 + quad * 8);
#pragma unroll
      for (int ct = 0; ct < 5; ++ct) {
        bf16x8 vb = *(const bf16x8*)(V_ + (ct * 16 + l16) * 88 + k2 * 32 + quad * 8);
#pragma unroll
        for (int it = 0; it < 2; ++it)
          o[it][ct] = __builtin_amdgcn_mfma_f32_16x16x32_bf16(pa[it], vb, o[it][ct], 0, 0, 0);
      }
    }
  }

  // final row-sum reduce (over l16) and write
#pragma unroll
  for (int it = 0; it < 2; ++it) {
#pragma unroll
    for (int r = 0; r < 4; ++r) {
      float l = lrow[it][r];
      l += __shfl_xor(l, 1, 64);
      l += __shfl_xor(l, 2, 64);
      l += __shfl_xor(l, 4, 64);
      l += __shfl_xor(l, 8, 64);
      float rinv = 1.0f / l;
      long long tok = (long long)c * CHUNK + qt * 256 + w * 32 + it * 16 + quad * 4 + r;
#pragma unroll
      for (int ct = 0; ct < 5; ++ct)
        attn[tok * HID + h * HD + ct * 16 + l16] = (bf16)(o[it][ct][r] * rinv);
    }
  }
}

// ---------------------------------------------------------------------------
extern "C" void kernel_launch(void* const* d_in, const int* in_sizes, int n_in,
                              void* d_out, int out_size, void* d_ws,
                              size_t ws_size, hipStream_t stream) {
  const float* x = (const float*)d_in[0];
  const float* cosp = (const float*)d_in[2];
  const float* sinp = (const float*)d_in[3];
  const float* wqkv = (const float*)d_in[4];
  const float* bqkv = (const float*)d_in[5];
  const float* wproj = (const float*)d_in[6];
  const float* bproj = (const float*)d_in[7];
  bf16* ws = (bf16*)d_ws;
  float* out = (float*)d_out;

  convert_kernel<<<35072, 256, 0, stream>>>(x, wqkv, wproj, ws);
  gemm_bt_kernel<0><<<dim3(128, 30), 256, 0, stream>>>(
      ws + OFF_XB, ws + OFF_WQKV, bqkv, ws, nullptr);
  rope_kernel<<<10240, 256, 0, stream>>>(cosp, sinp, ws);
  attn_kernel<<<dim3(256, 4), 512, 0, stream>>>(ws);
  gemm_bt_kernel<1><<<dim3(128, 10), 256, 0, stream>>>(
      ws + OFF_ATTN, ws + OFF_WPROJ, bproj, ws, out);
}